// Round 9
// baseline (125.704 us; speedup 1.0000x reference)
//
#include <hip/hip_runtime.h>
#include <math.h>

// ---------------- problem constants ----------------
namespace {
constexpr int Bn = 4, Sn = 8, Cn = 3, Himg = 256, Wimg = 256;
constexpr int Pn = 68, DS = 4, WIN = 8, STEPS = 10;
constexpr int HWi = Himg * Wimg;            // 65536
constexpr int NIMG = Bn * Sn;               // 32
constexpr int HD = Himg / DS, WD = Wimg / DS; // 64 x 64
constexpr int Kwin = (2 * WIN + 1) * (2 * WIN + 1); // 289
}

// ---------------- gray conversion + 1px-shifted copy ----------------
__global__ __launch_bounds__(256) void gray2_kernel(const float* __restrict__ in,
                                                    float* __restrict__ gray,
                                                    float* __restrict__ sh) {
    int idx = blockIdx.x * blockDim.x + threadIdx.x;   // float4 index
    int total = NIMG * HWi / 4;
    if (idx >= total) return;
    int img = idx / (HWi / 4);
    int off = idx % (HWi / 4);
    const float* base = in + (size_t)img * 3 * HWi;
    float4 c0 = ((const float4*)(base))[off];
    float4 c1 = ((const float4*)(base + HWi))[off];
    float4 c2 = ((const float4*)(base + 2 * HWi))[off];
    float4 g;
    g.x = 0.299f * c0.x + 0.587f * c1.x + 0.114f * c2.x;
    g.y = 0.299f * c0.y + 0.587f * c1.y + 0.114f * c2.y;
    g.z = 0.299f * c0.z + 0.587f * c1.z + 0.114f * c2.z;
    g.w = 0.299f * c0.w + 0.587f * c1.w + 0.114f * c2.w;
    // gray value of next global element (4*idx+4), for the shifted array
    float gn = 0.f;
    int gi = idx * 4 + 4;
    if (gi < NIMG * HWi) {
        int i2 = gi / HWi;
        int o2 = gi % HWi;
        const float* b2 = in + (size_t)i2 * 3 * HWi;
        gn = 0.299f * b2[o2] + 0.587f * b2[o2 + HWi] + 0.114f * b2[o2 + 2 * HWi];
    }
    ((float4*)(gray + (size_t)img * HWi))[off] = g;
    float4 s;
    s.x = g.y; s.y = g.z; s.z = g.w; s.w = gn;
    ((float4*)(sh + (size_t)img * HWi))[off] = s;
}

// ---------------- detector conv (3x3, stride 4, pad 0 == SAME here) ----------------
__global__ __launch_bounds__(256) void conv_kernel(const float* __restrict__ x,
                                                   const float* __restrict__ Wdet,
                                                   const float* __restrict__ bdet,
                                                   float* __restrict__ hm) {
    __shared__ float wsh[Pn * 27];
    __shared__ float bsh[Pn];
    __shared__ float insh[3][3][Wimg];
    int n = blockIdx.x >> 6;
    int oy = blockIdx.x & 63;
    int tid = threadIdx.x;
    for (int t = tid; t < Pn * 27; t += 256) wsh[t] = Wdet[t];
    if (tid < Pn) bsh[tid] = bdet[tid];
    for (int t = tid; t < 3 * 3 * Wimg; t += 256) {
        int c = t / (3 * Wimg);
        int r = (t / Wimg) % 3;
        int col = t % Wimg;
        insh[c][r][col] = x[(size_t)n * 3 * HWi + (size_t)c * HWi + (oy * 4 + r) * Wimg + col];
    }
    __syncthreads();
    int ox = tid & 63;
    int wid = tid >> 6;
    float in_reg[27];
    #pragma unroll
    for (int c = 0; c < 3; c++)
        #pragma unroll
        for (int ky = 0; ky < 3; ky++)
            #pragma unroll
            for (int kx = 0; kx < 3; kx++)
                in_reg[c * 9 + ky * 3 + kx] = insh[c][ky][ox * 4 + kx];
    #pragma unroll
    for (int i = 0; i < 17; i++) {
        int p = wid + i * 4;
        const float* w = &wsh[p * 27];
        float acc = bsh[p];
        #pragma unroll
        for (int j = 0; j < 27; j++) acc += w[j] * in_reg[j];
        hm[(size_t)n * Pn * 4096 + (size_t)p * 4096 + oy * 64 + ox] = acc;
    }
}

// ---------------- softmax / soft-argmax / scores ----------------
__global__ __launch_bounds__(256) void smax_kernel(const float* __restrict__ hm,
                                                   float* __restrict__ locs,
                                                   float* __restrict__ scos) {
    int row = blockIdx.x;   // n*Pn + p
    const float4* r = (const float4*)(hm + (size_t)row * 4096);
    int tid = threadIdx.x;
    float v[16];
    #pragma unroll
    for (int j = 0; j < 4; j++) {
        float4 q = r[tid + 256 * j];
        v[4 * j + 0] = q.x; v[4 * j + 1] = q.y; v[4 * j + 2] = q.z; v[4 * j + 3] = q.w;
    }
    float m = v[0];
    #pragma unroll
    for (int i = 1; i < 16; i++) m = fmaxf(m, v[i]);
    __shared__ float redm[4];
    #pragma unroll
    for (int o = 32; o; o >>= 1) m = fmaxf(m, __shfl_xor(m, o, 64));
    int wid = tid >> 6, lane = tid & 63;
    if (lane == 0) redm[wid] = m;
    __syncthreads();
    m = fmaxf(fmaxf(redm[0], redm[1]), fmaxf(redm[2], redm[3]));
    float s = 0.f, sx = 0.f, sy = 0.f;
    #pragma unroll
    for (int j = 0; j < 4; j++) {
        #pragma unroll
        for (int q = 0; q < 4; q++) {
            int e = (tid + 256 * j) * 4 + q;
            float ev = expf(v[4 * j + q] - m);
            s += ev;
            sx += ev * (float)(e & 63);
            sy += ev * (float)(e >> 6);
        }
    }
    #pragma unroll
    for (int o = 32; o; o >>= 1) {
        s  += __shfl_xor(s, o, 64);
        sx += __shfl_xor(sx, o, 64);
        sy += __shfl_xor(sy, o, 64);
    }
    __shared__ float reds[3][4];
    if (lane == 0) { reds[0][wid] = s; reds[1][wid] = sx; reds[2][wid] = sy; }
    __syncthreads();
    if (tid == 0) {
        float S_ = reds[0][0] + reds[0][1] + reds[0][2] + reds[0][3];
        float SX = reds[1][0] + reds[1][1] + reds[1][2] + reds[1][3];
        float SY = reds[2][0] + reds[2][1] + reds[2][2] + reds[2][3];
        locs[(size_t)row * 2 + 0] = SX / S_ * 4.0f;
        locs[(size_t)row * 2 + 1] = SY / S_ * 4.0f;
        scos[row] = m;
    }
}

// ---------------- DPP wave64 sum reduction (VALU-only) ----------------
template <int CTRL>
__device__ inline float dpp_add(float v) {
    int t = __builtin_amdgcn_update_dpp(0, __builtin_bit_cast(int, v), CTRL, 0xF, 0xF, true);
    return v + __builtin_bit_cast(float, t);
}

__device__ inline float wredw(float v) {
    v = dpp_add<0x111>(v);   // row_shr:1
    v = dpp_add<0x112>(v);   // row_shr:2
    v = dpp_add<0x114>(v);   // row_shr:4
    v = dpp_add<0x118>(v);   // row_shr:8
    v = dpp_add<0x142>(v);   // row_bcast:15
    v = dpp_add<0x143>(v);   // row_bcast:31
    int s = __builtin_amdgcn_readlane(__builtin_bit_cast(int, v), 63);
    return __builtin_bit_cast(float, s);
}

// ---------------- LK pair-load track step with per-lane cell cache ----------------
// oldI/newI: gray frames; oldS/newS: 1px-shifted copies (sh[i] == gray[i+1]).
// Slots j=0..3 fully active; slot 4 active lanes<33, gradients masked by s4w.
// GN loop: the 2x2 corner cells per slot are cached in registers keyed by the
// integer cell index; lanes reload (exec-masked) only when floor(q+v) crossed
// a cell boundary. Cell identity => bit-identical values => exact.
__device__ void lk_track_pair(const float* __restrict__ oldI, const float* __restrict__ oldS,
                              const float* __restrict__ newI, const float* __restrict__ newS,
                              float& px, float& py, const float* dxs, const float* dys,
                              float s4w) {
    const float XM = (float)(Wimg - 1.001);
    const float YM = (float)(Himg - 1.001);
    float I0[5], Ix[5], Iy[5], qx[5], qy[5];
    // ---- template phase: 4 pair-loads + 4 scalar loads per slot ----
    {
        float wx[5], wy[5];
        const float* pb[5];
        int xe[5], am[5], a0[5], a1[5], ap[5], xm[5], xp[5];
        #pragma unroll
        for (int j = 0; j < 5; j++) {
            qx[j] = px + dxs[j];
            qy[j] = py + dys[j];
            float x = fminf(fmaxf(qx[j], 0.0f), XM);
            float y = fminf(fmaxf(qy[j], 0.0f), YM);
            float x0f = floorf(x), y0f = floorf(y);
            wx[j] = x - x0f; wy[j] = y - y0f;
            int xi = (int)x0f, yi = (int)y0f;
            xe[j] = xi & ~1;
            pb[j] = (xi & 1) ? oldS : oldI;
            xm[j] = max(xi - 1, 0);
            xp[j] = min(xi + 2, Wimg - 1);
            a0[j] = yi * Wimg;
            a1[j] = a0[j] + Wimg;                 // yi+1 <= 255 always
            am[j] = max(yi - 1, 0) * Wimg;
            ap[j] = min(yi + 2, Himg - 1) * Wimg;
        }
        float2 Pm[5], P0[5], P1[5], Pp[5];
        float c0m[5], c0p[5], c1m[5], c1p[5];
        #pragma unroll
        for (int j = 0; j < 5; j++) {
            Pm[j] = *(const float2*)(pb[j] + am[j] + xe[j]);
            P0[j] = *(const float2*)(pb[j] + a0[j] + xe[j]);
            P1[j] = *(const float2*)(pb[j] + a1[j] + xe[j]);
            Pp[j] = *(const float2*)(pb[j] + ap[j] + xe[j]);
            c0m[j] = oldI[a0[j] + xm[j]];
            c0p[j] = oldI[a0[j] + xp[j]];
            c1m[j] = oldI[a1[j] + xm[j]];
            c1p[j] = oldI[a1[j] + xp[j]];
        }
        #pragma unroll
        for (int j = 0; j < 5; j++) {
            float m0 = Pm[j].x, m1 = Pm[j].y;
            float c00 = P0[j].x, c01 = P0[j].y;
            float c10 = P1[j].x, c11 = P1[j].y;
            float p0 = Pp[j].x, p1 = Pp[j].y;
            float u = 1.0f - wx[j], t = 1.0f - wy[j];
            I0[j] = t * (u * c00 + wx[j] * c01) + wy[j] * (u * c10 + wx[j] * c11);
            float gx00 = 0.5f * (c01 - c0m[j]);
            float gx01 = 0.5f * (c0p[j] - c00);
            float gx10 = 0.5f * (c11 - c1m[j]);
            float gx11 = 0.5f * (c1p[j] - c10);
            Ix[j] = t * (u * gx00 + wx[j] * gx01) + wy[j] * (u * gx10 + wx[j] * gx11);
            float gy00 = 0.5f * (c10 - m0);
            float gy01 = 0.5f * (c11 - m1);
            float gy10 = 0.5f * (p0 - c00);
            float gy11 = 0.5f * (p1 - c01);
            Iy[j] = t * (u * gy00 + wx[j] * gy01) + wy[j] * (u * gy10 + wx[j] * gy11);
        }
        Ix[4] *= s4w;
        Iy[4] *= s4w;
    }
    float gxx0 = 0.f, gxy0 = 0.f, gyy0 = 0.f;
    #pragma unroll
    for (int j = 0; j < 5; j++) { gxx0 += Ix[j] * Ix[j]; gxy0 += Ix[j] * Iy[j]; gyy0 += Iy[j] * Iy[j]; }
    float gxx = wredw(gxx0);
    float gxy = wredw(gxy0);
    float gyy = wredw(gyy0);
    float det = gxx * gyy - gxy * gxy + 1e-6f;
    float A = gyy / det, Bv = -gxy / det, D = gxx / det;  // Ginv
    float vx = 0.f, vy = 0.f;
    // ---- Gauss-Newton loop with register cell cache ----
    int   kc[5];
    float c00[5], c01[5], c10[5], c11[5];
    #pragma unroll
    for (int j = 0; j < 5; j++) kc[j] = -1;
    for (int it = 0; it < STEPS; ++it) {
        float bx = 0.f, by = 0.f;
        #pragma unroll
        for (int j = 0; j < 5; j++) {
            float x = fminf(fmaxf(qx[j] + vx, 0.0f), XM);
            float y = fminf(fmaxf(qy[j] + vy, 0.0f), YM);
            float xf = floorf(x), yf = floorf(y);
            float fx = x - xf, fy = y - yf;
            int xi = (int)xf, yi = (int)yf;
            int key = yi * Wimg + xi;
            if (key != kc[j]) {   // per-lane predicated reload (exec-masked)
                kc[j] = key;
                const float* pb = (xi & 1) ? newS : newI;
                int aa = yi * Wimg + (xi & ~1);
                float2 R0 = *(const float2*)(pb + aa);
                float2 R1 = *(const float2*)(pb + aa + Wimg);
                c00[j] = R0.x; c01[j] = R0.y; c10[j] = R1.x; c11[j] = R1.y;
            }
            float u = 1.0f - fx, t = 1.0f - fy;
            float I1 = t * (u * c00[j] + fx * c01[j]) + fy * (u * c10[j] + fx * c11[j]);
            float err = I0[j] - I1;
            bx += err * Ix[j];
            by += err * Iy[j];
        }
        bx = wredw(bx); by = wredw(by);
        vx += A * bx + Bv * by;
        vy += Bv * bx + D * by;
    }
    px += vx; py += vy;
}

__global__ __launch_bounds__(64) void lk_pair_kernel(const float* __restrict__ gray,
                                                     const float* __restrict__ sh,
                                                     const float* __restrict__ locs,
                                                     float* __restrict__ nextPts,
                                                     float* __restrict__ fbackPts,
                                                     float* __restrict__ backPts) {
    int g = blockIdx.x;
    int typ = g / (Bn * Pn);
    int r = g % (Bn * Pn);
    int b = r / Pn;
    int p = r % Pn;
    int lane = threadIdx.x;
    const float* G = gray + (size_t)b * Sn * HWi;
    const float* S = sh + (size_t)b * Sn * HWi;
    float dxs[5], dys[5];
    #pragma unroll
    for (int j = 0; j < 4; j++) {
        int k = lane + 64 * j;
        dxs[j] = (float)(k % 17 - 8);
        dys[j] = (float)(k / 17 - 8);
    }
    {
        int k4 = (lane < Kwin - 256) ? 256 + lane : 256;
        dxs[4] = (float)(k4 % 17 - 8);
        dys[4] = (float)(k4 / 17 - 8);
    }
    float s4w = (lane < Kwin - 256) ? 1.0f : 0.0f;
    auto LIDX = [&](int s) { return (((size_t)b * Sn + s) * Pn + p) * 2; };
    if (typ == 0) {
        float px = locs[LIDX(0)], py = locs[LIDX(0) + 1];
        if (lane == 0) { nextPts[LIDX(0)] = px; nextPts[LIDX(0) + 1] = py; }
        for (int s = 0; s < 7; s++) {
            lk_track_pair(G + s * HWi, S + s * HWi, G + (s + 1) * HWi, S + (s + 1) * HWi,
                          px, py, dxs, dys, s4w);
            if (lane == 0) { nextPts[LIDX(s + 1)] = px; nextPts[LIDX(s + 1) + 1] = py; }
        }
        if (lane == 0) { fbackPts[LIDX(7)] = px; fbackPts[LIDX(7) + 1] = py; }
        for (int i = 0; i < 7; i++) {
            lk_track_pair(G + (7 - i) * HWi, S + (7 - i) * HWi, G + (6 - i) * HWi, S + (6 - i) * HWi,
                          px, py, dxs, dys, s4w);
            if (lane == 0) { fbackPts[LIDX(6 - i)] = px; fbackPts[LIDX(6 - i) + 1] = py; }
        }
    } else {
        float px = locs[LIDX(7)], py = locs[LIDX(7) + 1];
        if (lane == 0) { backPts[LIDX(7)] = px; backPts[LIDX(7) + 1] = py; }
        for (int i = 0; i < 7; i++) {
            lk_track_pair(G + (7 - i) * HWi, S + (7 - i) * HWi, G + (6 - i) * HWi, S + (6 - i) * HWi,
                          px, py, dxs, dys, s4w);
            if (lane == 0) { backPts[LIDX(6 - i)] = px; backPts[LIDX(6 - i) + 1] = py; }
        }
    }
}

// ---------------- fallback (ws too small): on-the-fly gray, scalar gathers ----------------
__device__ inline float px_fly(const float* __restrict__ im, int idx) {
    return 0.299f * im[idx] + 0.587f * im[idx + HWi] + 0.114f * im[idx + 2 * HWi];
}

__device__ void lk_track_fly(const float* __restrict__ oldI, const float* __restrict__ newI,
                             float& px, float& py, const float* dxs, const float* dys,
                             float s4w) {
    const float XM = (float)(Wimg - 1.001);
    const float YM = (float)(Himg - 1.001);
    float I0[5], Ix[5], Iy[5], qx[5], qy[5];
    {
        float wx[5], wy[5];
        int am[5], a0[5], a1[5], ap[5], xm[5], x0[5], x1[5], xp[5];
        #pragma unroll
        for (int j = 0; j < 5; j++) {
            qx[j] = px + dxs[j]; qy[j] = py + dys[j];
            float x = fminf(fmaxf(qx[j], 0.0f), XM);
            float y = fminf(fmaxf(qy[j], 0.0f), YM);
            float x0f = floorf(x), y0f = floorf(y);
            wx[j] = x - x0f; wy[j] = y - y0f;
            int xi = (int)x0f, yi = (int)y0f;
            x0[j] = xi; x1[j] = min(xi + 1, Wimg - 1);
            xm[j] = max(xi - 1, 0); xp[j] = min(xi + 2, Wimg - 1);
            a0[j] = yi * Wimg;
            a1[j] = min(yi + 1, Himg - 1) * Wimg;
            am[j] = max(yi - 1, 0) * Wimg;
            ap[j] = min(yi + 2, Himg - 1) * Wimg;
        }
        #pragma unroll
        for (int j = 0; j < 5; j++) {
            float m0 = px_fly(oldI, am[j] + x0[j]), m1 = px_fly(oldI, am[j] + x1[j]);
            float c0m = px_fly(oldI, a0[j] + xm[j]), c00 = px_fly(oldI, a0[j] + x0[j]);
            float c01 = px_fly(oldI, a0[j] + x1[j]), c0p = px_fly(oldI, a0[j] + xp[j]);
            float c1m = px_fly(oldI, a1[j] + xm[j]), c10 = px_fly(oldI, a1[j] + x0[j]);
            float c11 = px_fly(oldI, a1[j] + x1[j]), c1p = px_fly(oldI, a1[j] + xp[j]);
            float p0 = px_fly(oldI, ap[j] + x0[j]), p1 = px_fly(oldI, ap[j] + x1[j]);
            float u = 1.0f - wx[j], t = 1.0f - wy[j];
            I0[j] = t * (u * c00 + wx[j] * c01) + wy[j] * (u * c10 + wx[j] * c11);
            Ix[j] = t * (u * 0.5f * (c01 - c0m) + wx[j] * 0.5f * (c0p - c00))
                  + wy[j] * (u * 0.5f * (c11 - c1m) + wx[j] * 0.5f * (c1p - c10));
            Iy[j] = t * (u * 0.5f * (c10 - m0) + wx[j] * 0.5f * (c11 - m1))
                  + wy[j] * (u * 0.5f * (p0 - c00) + wx[j] * 0.5f * (p1 - c01));
        }
        Ix[4] *= s4w; Iy[4] *= s4w;
    }
    float gxx = 0.f, gxy = 0.f, gyy = 0.f;
    #pragma unroll
    for (int j = 0; j < 5; j++) { gxx += Ix[j] * Ix[j]; gxy += Ix[j] * Iy[j]; gyy += Iy[j] * Iy[j]; }
    gxx = wredw(gxx); gxy = wredw(gxy); gyy = wredw(gyy);
    float det = gxx * gyy - gxy * gxy + 1e-6f;
    float A = gyy / det, Bv = -gxy / det, D = gxx / det;
    float vx = 0.f, vy = 0.f;
    for (int it = 0; it < STEPS; ++it) {
        float bx = 0.f, by = 0.f;
        #pragma unroll
        for (int j = 0; j < 5; j++) {
            float x = fminf(fmaxf(qx[j] + vx, 0.0f), XM);
            float y = fminf(fmaxf(qy[j] + vy, 0.0f), YM);
            float x0f = floorf(x), y0f = floorf(y);
            float fxx = x - x0f, fyy = y - y0f;
            int xi = (int)x0f, yi = (int)y0f;
            int ad = yi * Wimg + xi;
            int d1 = (xi < Wimg - 1) ? 1 : 0;
            int d2 = (yi < Himg - 1) ? Wimg : 0;
            float v00 = px_fly(newI, ad), v01 = px_fly(newI, ad + d1);
            float v10 = px_fly(newI, ad + d2), v11 = px_fly(newI, ad + d2 + d1);
            float u = 1.0f - fxx, t = 1.0f - fyy;
            float I1 = t * (u * v00 + fxx * v01) + fyy * (u * v10 + fxx * v11);
            float err = I0[j] - I1;
            bx += err * Ix[j];
            by += err * Iy[j];
        }
        bx = wredw(bx); by = wredw(by);
        vx += A * bx + Bv * by;
        vy += Bv * bx + D * by;
    }
    px += vx; py += vy;
}

__global__ __launch_bounds__(64) void lk_fly_kernel(const float* __restrict__ in,
                                                    const float* __restrict__ locs,
                                                    float* __restrict__ nextPts,
                                                    float* __restrict__ fbackPts,
                                                    float* __restrict__ backPts) {
    constexpr size_t FS = (size_t)3 * HWi;
    int g = blockIdx.x;
    int typ = g / (Bn * Pn);
    int r = g % (Bn * Pn);
    int b = r / Pn;
    int p = r % Pn;
    int lane = threadIdx.x;
    const float* G = in + (size_t)b * Sn * FS;
    float dxs[5], dys[5];
    #pragma unroll
    for (int j = 0; j < 4; j++) {
        int k = lane + 64 * j;
        dxs[j] = (float)(k % 17 - 8);
        dys[j] = (float)(k / 17 - 8);
    }
    {
        int k4 = (lane < Kwin - 256) ? 256 + lane : 256;
        dxs[4] = (float)(k4 % 17 - 8);
        dys[4] = (float)(k4 / 17 - 8);
    }
    float s4w = (lane < Kwin - 256) ? 1.0f : 0.0f;
    auto LIDX = [&](int s) { return (((size_t)b * Sn + s) * Pn + p) * 2; };
    if (typ == 0) {
        float px = locs[LIDX(0)], py = locs[LIDX(0) + 1];
        if (lane == 0) { nextPts[LIDX(0)] = px; nextPts[LIDX(0) + 1] = py; }
        for (int s = 0; s < 7; s++) {
            lk_track_fly(G + s * FS, G + (s + 1) * FS, px, py, dxs, dys, s4w);
            if (lane == 0) { nextPts[LIDX(s + 1)] = px; nextPts[LIDX(s + 1) + 1] = py; }
        }
        if (lane == 0) { fbackPts[LIDX(7)] = px; fbackPts[LIDX(7) + 1] = py; }
        for (int i = 0; i < 7; i++) {
            lk_track_fly(G + (7 - i) * FS, G + (6 - i) * FS, px, py, dxs, dys, s4w);
            if (lane == 0) { fbackPts[LIDX(6 - i)] = px; fbackPts[LIDX(6 - i) + 1] = py; }
        }
    } else {
        float px = locs[LIDX(7)], py = locs[LIDX(7) + 1];
        if (lane == 0) { backPts[LIDX(7)] = px; backPts[LIDX(7) + 1] = py; }
        for (int i = 0; i < 7; i++) {
            lk_track_fly(G + (7 - i) * FS, G + (6 - i) * FS, px, py, dxs, dys, s4w);
            if (lane == 0) { backPts[LIDX(6 - i)] = px; backPts[LIDX(6 - i) + 1] = py; }
        }
    }
}

// ---------------- launch ----------------
extern "C" void kernel_launch(void* const* d_in, const int* in_sizes, int n_in,
                              void* d_out, int out_size, void* d_ws, size_t ws_size,
                              hipStream_t stream) {
    const float* inputs = (const float*)d_in[0];
    const float* Wdet = (const float*)d_in[1];
    const float* bdet = (const float*)d_in[2];
    float* out = (float*)d_out;

    const size_t N_hm = (size_t)Bn * Sn * Pn * HD * WD;   // 8,912,896
    const size_t N_pts = (size_t)Bn * Sn * Pn * 2;        // 4352
    float* hm = out;
    float* locs = out + N_hm;
    float* scos = locs + N_pts;
    float* nextPts = scos + (size_t)Bn * Sn * Pn;
    float* fbackPts = nextPts + N_pts;
    float* backPts = fbackPts + N_pts;

    conv_kernel<<<NIMG * 64, 256, 0, stream>>>(inputs, Wdet, bdet, hm);
    smax_kernel<<<NIMG * Pn, 256, 0, stream>>>(hm, locs, scos);

    const size_t gray_elems = (size_t)NIMG * HWi;
    if (ws_size >= 2 * gray_elems * sizeof(float)) {
        float* gray = (float*)d_ws;
        float* sh = gray + gray_elems;
        gray2_kernel<<<(NIMG * HWi / 4 + 255) / 256, 256, 0, stream>>>(inputs, gray, sh);
        lk_pair_kernel<<<2 * Bn * Pn, 64, 0, stream>>>(gray, sh, locs, nextPts, fbackPts, backPts);
    } else {
        lk_fly_kernel<<<2 * Bn * Pn, 64, 0, stream>>>(inputs, locs, nextPts, fbackPts, backPts);
    }
}

// Round 10
// 113.295 us; speedup vs baseline: 1.1095x; 1.1095x over previous
//
#include <hip/hip_runtime.h>
#include <math.h>

// ---------------- problem constants ----------------
namespace {
constexpr int Bn = 4, Sn = 8, Cn = 3, Himg = 256, Wimg = 256;
constexpr int Pn = 68, DS = 4, WIN = 8, STEPS = 10;
constexpr int HWi = Himg * Wimg;            // 65536
constexpr int NIMG = Bn * Sn;               // 32
constexpr int HD = Himg / DS, WD = Wimg / DS; // 64 x 64
constexpr int Kwin = (2 * WIN + 1) * (2 * WIN + 1); // 289
// row-pair image: P2r[k][x] = (gray[max(k-1,0)][x], gray[min(k,255)][x]), k=0..256
constexpr int P2ROWS = 257;
constexpr int P2FR = P2ROWS * 256;           // 65792 float2 per frame
constexpr int NSHIFT = NIMG * P2FR;          // offset from P2r to P2rs (float2 units)
}

// ---------------- detector conv (3x3, stride 4, pad 0 == SAME here) ----------------
__global__ __launch_bounds__(256) void conv_kernel(const float* __restrict__ x,
                                                   const float* __restrict__ Wdet,
                                                   const float* __restrict__ bdet,
                                                   float* __restrict__ hm) {
    __shared__ float wsh[Pn * 27];
    __shared__ float bsh[Pn];
    __shared__ float insh[3][3][Wimg];
    int n = blockIdx.x >> 6;
    int oy = blockIdx.x & 63;
    int tid = threadIdx.x;
    for (int t = tid; t < Pn * 27; t += 256) wsh[t] = Wdet[t];
    if (tid < Pn) bsh[tid] = bdet[tid];
    for (int t = tid; t < 3 * 3 * Wimg; t += 256) {
        int c = t / (3 * Wimg);
        int r = (t / Wimg) % 3;
        int col = t % Wimg;
        insh[c][r][col] = x[(size_t)n * 3 * HWi + (size_t)c * HWi + (oy * 4 + r) * Wimg + col];
    }
    __syncthreads();
    int ox = tid & 63;
    int wid = tid >> 6;
    float in_reg[27];
    #pragma unroll
    for (int c = 0; c < 3; c++)
        #pragma unroll
        for (int ky = 0; ky < 3; ky++)
            #pragma unroll
            for (int kx = 0; kx < 3; kx++)
                in_reg[c * 9 + ky * 3 + kx] = insh[c][ky][ox * 4 + kx];
    #pragma unroll
    for (int i = 0; i < 17; i++) {
        int p = wid + i * 4;
        const float* w = &wsh[p * 27];
        float acc = bsh[p];
        #pragma unroll
        for (int j = 0; j < 27; j++) acc += w[j] * in_reg[j];
        hm[(size_t)n * Pn * 4096 + (size_t)p * 4096 + oy * 64 + ox] = acc;
    }
}

// ---------------- softmax / soft-argmax / scores ----------------
__global__ __launch_bounds__(256) void smax_kernel(const float* __restrict__ hm,
                                                   float* __restrict__ locs,
                                                   float* __restrict__ scos) {
    int row = blockIdx.x;   // n*Pn + p
    const float4* r = (const float4*)(hm + (size_t)row * 4096);
    int tid = threadIdx.x;
    float v[16];
    #pragma unroll
    for (int j = 0; j < 4; j++) {
        float4 q = r[tid + 256 * j];
        v[4 * j + 0] = q.x; v[4 * j + 1] = q.y; v[4 * j + 2] = q.z; v[4 * j + 3] = q.w;
    }
    float m = v[0];
    #pragma unroll
    for (int i = 1; i < 16; i++) m = fmaxf(m, v[i]);
    __shared__ float redm[4];
    #pragma unroll
    for (int o = 32; o; o >>= 1) m = fmaxf(m, __shfl_xor(m, o, 64));
    int wid = tid >> 6, lane = tid & 63;
    if (lane == 0) redm[wid] = m;
    __syncthreads();
    m = fmaxf(fmaxf(redm[0], redm[1]), fmaxf(redm[2], redm[3]));
    float s = 0.f, sx = 0.f, sy = 0.f;
    #pragma unroll
    for (int j = 0; j < 4; j++) {
        #pragma unroll
        for (int q = 0; q < 4; q++) {
            int e = (tid + 256 * j) * 4 + q;
            float ev = expf(v[4 * j + q] - m);
            s += ev;
            sx += ev * (float)(e & 63);
            sy += ev * (float)(e >> 6);
        }
    }
    #pragma unroll
    for (int o = 32; o; o >>= 1) {
        s  += __shfl_xor(s, o, 64);
        sx += __shfl_xor(sx, o, 64);
        sy += __shfl_xor(sy, o, 64);
    }
    __shared__ float reds[3][4];
    if (lane == 0) { reds[0][wid] = s; reds[1][wid] = sx; reds[2][wid] = sy; }
    __syncthreads();
    if (tid == 0) {
        float S_ = reds[0][0] + reds[0][1] + reds[0][2] + reds[0][3];
        float SX = reds[1][0] + reds[1][1] + reds[1][2] + reds[1][3];
        float SY = reds[2][0] + reds[2][1] + reds[2][2] + reds[2][3];
        locs[(size_t)row * 2 + 0] = SX / S_ * 4.0f;
        locs[(size_t)row * 2 + 1] = SY / S_ * 4.0f;
        scos[row] = m;
    }
}

// ---------------- gray -> row-pair images P2r / P2rs ----------------
// P2r[k][x] = (g[max(k-1,0)][x], g[min(k,255)][x]); P2rs[i] = P2r[i+1] (flat, cols 254/255 garbage-ok)
__global__ __launch_bounds__(256) void grayP2_kernel(const float* __restrict__ in,
                                                     float2* __restrict__ P2r,
                                                     float2* __restrict__ P2rs) {
    __shared__ float g[9][257];
    int blk = blockIdx.x;
    int n = blk / 33, q = blk % 33;
    int tid = threadIdx.x;
    const float* base = in + (size_t)n * 3 * HWi;
    #pragma unroll
    for (int r = 0; r < 9; r++) {
        int row = min(max(8 * q - 1 + r, 0), 255);
        int a = row * Wimg + tid;
        g[r][tid] = 0.299f * base[a] + 0.587f * base[a + HWi] + 0.114f * base[a + 2 * HWi];
    }
    if (tid < 9) g[tid][256] = g[tid][255];   // neighbor pad (values unread downstream)
    __syncthreads();
    float2* pr = P2r + (size_t)n * P2FR;
    float2* ps = P2rs + (size_t)n * P2FR;
    #pragma unroll
    for (int j = 0; j < 8; j++) {
        int k = 8 * q + j;
        if (k <= 256) {
            float a = g[j][tid], b = g[j + 1][tid];
            pr[k * 256 + tid] = make_float2(a, b);
            float a2 = g[j][tid + 1], b2 = g[j + 1][tid + 1];
            ps[k * 256 + tid] = make_float2(a2, b2);
        }
    }
}

// ---------------- DPP wave64 sum reduction (VALU-only) ----------------
template <int CTRL>
__device__ inline float dpp_add(float v) {
    int t = __builtin_amdgcn_update_dpp(0, __builtin_bit_cast(int, v), CTRL, 0xF, 0xF, true);
    return v + __builtin_bit_cast(float, t);
}

__device__ inline float wredw(float v) {
    v = dpp_add<0x111>(v);   // row_shr:1
    v = dpp_add<0x112>(v);   // row_shr:2
    v = dpp_add<0x114>(v);   // row_shr:4
    v = dpp_add<0x118>(v);   // row_shr:8
    v = dpp_add<0x142>(v);   // row_bcast:15
    v = dpp_add<0x143>(v);   // row_bcast:31
    int s = __builtin_amdgcn_readlane(__builtin_bit_cast(int, v), 63);
    return __builtin_bit_cast(float, s);
}

// ---------------- LK track step on row-pair images (1 wave/chain) ----------------
// Po/Pn: per-frame P2r bases (old/new); parity-shifted copy at +NSHIFT.
// GN iter: ONE dwordx4 per slot = all 4 bilinear corners.
__device__ void lk_track_p2(const float2* __restrict__ Po, const float2* __restrict__ Pn,
                            float& px, float& py, const float* dxs, const float* dys,
                            float s4w) {
    const float XM = (float)(Wimg - 1.001);
    const float YM = (float)(Himg - 1.001);
    float I0[5], Ix[5], Iy[5], qx[5], qy[5];
    // ---- template phase: 2 dwordx4 + 2 float2 per slot ----
    {
        float wx[5], wy[5];
        int idx[5], sb[5], xm[5], xp[5];
        #pragma unroll
        for (int j = 0; j < 5; j++) {
            qx[j] = px + dxs[j];
            qy[j] = py + dys[j];
            float x = fminf(fmaxf(qx[j], 0.0f), XM);
            float y = fminf(fmaxf(qy[j], 0.0f), YM);
            float xf = floorf(x), yf = floorf(y);
            wx[j] = x - xf; wy[j] = y - yf;
            int xi = (int)xf, yi = (int)yf;
            int col = xi & ~1;
            idx[j] = yi * 256 + col + ((xi & 1) ? NSHIFT : 0);
            sb[j] = (yi + 1) * 256;
            xm[j] = max(xi - 1, 0);
            xp[j] = min(xi + 2, Wimg - 1);
        }
        float4 A[5], B[5];
        float2 S1[5], S2[5];
        #pragma unroll
        for (int j = 0; j < 5; j++) {
            A[j] = *reinterpret_cast<const float4*>(Po + idx[j]);         // (m0,c00,m1,c01)
            B[j] = *reinterpret_cast<const float4*>(Po + idx[j] + 512);   // (c10,p0,c11,p1)
            S1[j] = Po[sb[j] + xm[j]];                                    // (c0m,c1m)
            S2[j] = Po[sb[j] + xp[j]];                                    // (c0p,c1p)
        }
        #pragma unroll
        for (int j = 0; j < 5; j++) {
            float m0 = A[j].x, c00 = A[j].y, m1 = A[j].z, c01 = A[j].w;
            float c10 = B[j].x, p0 = B[j].y, c11 = B[j].z, p1 = B[j].w;
            float c0m = S1[j].x, c1m = S1[j].y, c0p = S2[j].x, c1p = S2[j].y;
            float u = 1.0f - wx[j], t = 1.0f - wy[j];
            I0[j] = t * (u * c00 + wx[j] * c01) + wy[j] * (u * c10 + wx[j] * c11);
            float gx00 = 0.5f * (c01 - c0m);
            float gx01 = 0.5f * (c0p - c00);
            float gx10 = 0.5f * (c11 - c1m);
            float gx11 = 0.5f * (c1p - c10);
            Ix[j] = t * (u * gx00 + wx[j] * gx01) + wy[j] * (u * gx10 + wx[j] * gx11);
            float gy00 = 0.5f * (c10 - m0);
            float gy01 = 0.5f * (c11 - m1);
            float gy10 = 0.5f * (p0 - c00);
            float gy11 = 0.5f * (p1 - c01);
            Iy[j] = t * (u * gy00 + wx[j] * gy01) + wy[j] * (u * gy10 + wx[j] * gy11);
        }
        Ix[4] *= s4w;
        Iy[4] *= s4w;
    }
    float gxx = 0.f, gxy = 0.f, gyy = 0.f;
    #pragma unroll
    for (int j = 0; j < 5; j++) { gxx += Ix[j] * Ix[j]; gxy += Ix[j] * Iy[j]; gyy += Iy[j] * Iy[j]; }
    gxx = wredw(gxx); gxy = wredw(gxy); gyy = wredw(gyy);
    float det = gxx * gyy - gxy * gxy + 1e-6f;
    float A = gyy / det, Bv = -gxy / det, D = gxx / det;  // Ginv
    float vx = 0.f, vy = 0.f;
    // ---- Gauss-Newton loop: 5 dwordx4 gathers per iter ----
    for (int it = 0; it < STEPS; ++it) {
        float fx[5], fy[5];
        int id[5];
        #pragma unroll
        for (int j = 0; j < 5; j++) {
            float x = fminf(fmaxf(qx[j] + vx, 0.0f), XM);
            float y = fminf(fmaxf(qy[j] + vy, 0.0f), YM);
            float xf = floorf(x), yf = floorf(y);
            fx[j] = x - xf; fy[j] = y - yf;
            int xi = (int)xf, yi = (int)yf;
            id[j] = (yi + 1) * 256 + (xi & ~1) + ((xi & 1) ? NSHIFT : 0);
        }
        float4 Q[5];
        #pragma unroll
        for (int j = 0; j < 5; j++) Q[j] = *reinterpret_cast<const float4*>(Pn + id[j]);
        float bx = 0.f, by = 0.f;
        #pragma unroll
        for (int j = 0; j < 5; j++) {
            // Q = (v00, v10, v01, v11)
            float u = 1.0f - fx[j], t = 1.0f - fy[j];
            float I1 = t * (u * Q[j].x + fx[j] * Q[j].z) + fy[j] * (u * Q[j].y + fx[j] * Q[j].w);
            float err = I0[j] - I1;
            bx += err * Ix[j];
            by += err * Iy[j];
        }
        bx = wredw(bx); by = wredw(by);
        vx += A * bx + Bv * by;
        vy += Bv * bx + D * by;
    }
    px += vx; py += vy;
}

__global__ __launch_bounds__(64) void lk_p2_kernel(const float2* __restrict__ P2r,
                                                   const float* __restrict__ locs,
                                                   float* __restrict__ nextPts,
                                                   float* __restrict__ fbackPts,
                                                   float* __restrict__ backPts) {
    int g = blockIdx.x;
    int typ = g / (Bn * Pn);
    int r = g % (Bn * Pn);
    int b = r / Pn;
    int p = r % Pn;
    int lane = threadIdx.x;
    const float2* F = P2r + (size_t)b * Sn * P2FR;
    float dxs[5], dys[5];
    #pragma unroll
    for (int j = 0; j < 4; j++) {
        int k = lane + 64 * j;
        dxs[j] = (float)(k % 17 - 8);
        dys[j] = (float)(k / 17 - 8);
    }
    {
        int k4 = (lane < Kwin - 256) ? 256 + lane : 256;
        dxs[4] = (float)(k4 % 17 - 8);
        dys[4] = (float)(k4 / 17 - 8);
    }
    float s4w = (lane < Kwin - 256) ? 1.0f : 0.0f;
    auto LIDX = [&](int s) { return (((size_t)b * Sn + s) * Pn + p) * 2; };
    if (typ == 0) {
        float px = locs[LIDX(0)], py = locs[LIDX(0) + 1];
        if (lane == 0) { nextPts[LIDX(0)] = px; nextPts[LIDX(0) + 1] = py; }
        for (int s = 0; s < 7; s++) {
            lk_track_p2(F + s * P2FR, F + (s + 1) * P2FR, px, py, dxs, dys, s4w);
            if (lane == 0) { nextPts[LIDX(s + 1)] = px; nextPts[LIDX(s + 1) + 1] = py; }
        }
        if (lane == 0) { fbackPts[LIDX(7)] = px; fbackPts[LIDX(7) + 1] = py; }
        for (int i = 0; i < 7; i++) {
            lk_track_p2(F + (7 - i) * P2FR, F + (6 - i) * P2FR, px, py, dxs, dys, s4w);
            if (lane == 0) { fbackPts[LIDX(6 - i)] = px; fbackPts[LIDX(6 - i) + 1] = py; }
        }
    } else {
        float px = locs[LIDX(7)], py = locs[LIDX(7) + 1];
        if (lane == 0) { backPts[LIDX(7)] = px; backPts[LIDX(7) + 1] = py; }
        for (int i = 0; i < 7; i++) {
            lk_track_p2(F + (7 - i) * P2FR, F + (6 - i) * P2FR, px, py, dxs, dys, s4w);
            if (lane == 0) { backPts[LIDX(6 - i)] = px; backPts[LIDX(6 - i) + 1] = py; }
        }
    }
}

// ================= fallback tier 2: r7 pair path (ws >= 16.8 MB) =================
__global__ __launch_bounds__(256) void gray2_kernel(const float* __restrict__ in,
                                                    float* __restrict__ gray,
                                                    float* __restrict__ sh) {
    int idx = blockIdx.x * blockDim.x + threadIdx.x;
    int total = NIMG * HWi / 4;
    if (idx >= total) return;
    int img = idx / (HWi / 4);
    int off = idx % (HWi / 4);
    const float* base = in + (size_t)img * 3 * HWi;
    float4 c0 = ((const float4*)(base))[off];
    float4 c1 = ((const float4*)(base + HWi))[off];
    float4 c2 = ((const float4*)(base + 2 * HWi))[off];
    float4 g;
    g.x = 0.299f * c0.x + 0.587f * c1.x + 0.114f * c2.x;
    g.y = 0.299f * c0.y + 0.587f * c1.y + 0.114f * c2.y;
    g.z = 0.299f * c0.z + 0.587f * c1.z + 0.114f * c2.z;
    g.w = 0.299f * c0.w + 0.587f * c1.w + 0.114f * c2.w;
    float gn = 0.f;
    int gi = idx * 4 + 4;
    if (gi < NIMG * HWi) {
        int i2 = gi / HWi;
        int o2 = gi % HWi;
        const float* b2 = in + (size_t)i2 * 3 * HWi;
        gn = 0.299f * b2[o2] + 0.587f * b2[o2 + HWi] + 0.114f * b2[o2 + 2 * HWi];
    }
    ((float4*)(gray + (size_t)img * HWi))[off] = g;
    float4 s;
    s.x = g.y; s.y = g.z; s.z = g.w; s.w = gn;
    ((float4*)(sh + (size_t)img * HWi))[off] = s;
}

__device__ void lk_track_pair(const float* __restrict__ oldI, const float* __restrict__ oldS,
                              const float* __restrict__ newI, const float* __restrict__ newS,
                              float& px, float& py, const float* dxs, const float* dys,
                              float s4w) {
    const float XM = (float)(Wimg - 1.001);
    const float YM = (float)(Himg - 1.001);
    float I0[5], Ix[5], Iy[5], qx[5], qy[5];
    {
        float wx[5], wy[5];
        const float* pb[5];
        int xe[5], am[5], a0[5], a1[5], ap[5], xm[5], xp[5];
        #pragma unroll
        for (int j = 0; j < 5; j++) {
            qx[j] = px + dxs[j];
            qy[j] = py + dys[j];
            float x = fminf(fmaxf(qx[j], 0.0f), XM);
            float y = fminf(fmaxf(qy[j], 0.0f), YM);
            float x0f = floorf(x), y0f = floorf(y);
            wx[j] = x - x0f; wy[j] = y - y0f;
            int xi = (int)x0f, yi = (int)y0f;
            xe[j] = xi & ~1;
            pb[j] = (xi & 1) ? oldS : oldI;
            xm[j] = max(xi - 1, 0);
            xp[j] = min(xi + 2, Wimg - 1);
            a0[j] = yi * Wimg;
            a1[j] = a0[j] + Wimg;
            am[j] = max(yi - 1, 0) * Wimg;
            ap[j] = min(yi + 2, Himg - 1) * Wimg;
        }
        float2 Pm[5], P0[5], P1[5], Pp[5];
        float c0m[5], c0p[5], c1m[5], c1p[5];
        #pragma unroll
        for (int j = 0; j < 5; j++) {
            Pm[j] = *(const float2*)(pb[j] + am[j] + xe[j]);
            P0[j] = *(const float2*)(pb[j] + a0[j] + xe[j]);
            P1[j] = *(const float2*)(pb[j] + a1[j] + xe[j]);
            Pp[j] = *(const float2*)(pb[j] + ap[j] + xe[j]);
            c0m[j] = oldI[a0[j] + xm[j]];
            c0p[j] = oldI[a0[j] + xp[j]];
            c1m[j] = oldI[a1[j] + xm[j]];
            c1p[j] = oldI[a1[j] + xp[j]];
        }
        #pragma unroll
        for (int j = 0; j < 5; j++) {
            float m0 = Pm[j].x, m1 = Pm[j].y;
            float c00 = P0[j].x, c01 = P0[j].y;
            float c10 = P1[j].x, c11 = P1[j].y;
            float p0 = Pp[j].x, p1 = Pp[j].y;
            float u = 1.0f - wx[j], t = 1.0f - wy[j];
            I0[j] = t * (u * c00 + wx[j] * c01) + wy[j] * (u * c10 + wx[j] * c11);
            float gx00 = 0.5f * (c01 - c0m[j]);
            float gx01 = 0.5f * (c0p[j] - c00);
            float gx10 = 0.5f * (c11 - c1m[j]);
            float gx11 = 0.5f * (c1p[j] - c10);
            Ix[j] = t * (u * gx00 + wx[j] * gx01) + wy[j] * (u * gx10 + wx[j] * gx11);
            float gy00 = 0.5f * (c10 - m0);
            float gy01 = 0.5f * (c11 - m1);
            float gy10 = 0.5f * (p0 - c00);
            float gy11 = 0.5f * (p1 - c01);
            Iy[j] = t * (u * gy00 + wx[j] * gy01) + wy[j] * (u * gy10 + wx[j] * gy11);
        }
        Ix[4] *= s4w;
        Iy[4] *= s4w;
    }
    float gxx = 0.f, gxy = 0.f, gyy = 0.f;
    #pragma unroll
    for (int j = 0; j < 5; j++) { gxx += Ix[j] * Ix[j]; gxy += Ix[j] * Iy[j]; gyy += Iy[j] * Iy[j]; }
    gxx = wredw(gxx); gxy = wredw(gxy); gyy = wredw(gyy);
    float det = gxx * gyy - gxy * gxy + 1e-6f;
    float A = gyy / det, Bv = -gxy / det, D = gxx / det;
    float vx = 0.f, vy = 0.f;
    for (int it = 0; it < STEPS; ++it) {
        float fx[5], fy[5];
        const float* pb[5];
        int aa[5];
        #pragma unroll
        for (int j = 0; j < 5; j++) {
            float x = fminf(fmaxf(qx[j] + vx, 0.0f), XM);
            float y = fminf(fmaxf(qy[j] + vy, 0.0f), YM);
            float x0f = floorf(x), y0f = floorf(y);
            fx[j] = x - x0f; fy[j] = y - y0f;
            int xi = (int)x0f, yi = (int)y0f;
            pb[j] = (xi & 1) ? newS : newI;
            aa[j] = yi * Wimg + (xi & ~1);
        }
        float2 R0[5], R1[5];
        #pragma unroll
        for (int j = 0; j < 5; j++) {
            R0[j] = *(const float2*)(pb[j] + aa[j]);
            R1[j] = *(const float2*)(pb[j] + aa[j] + Wimg);
        }
        float bx = 0.f, by = 0.f;
        #pragma unroll
        for (int j = 0; j < 5; j++) {
            float u = 1.0f - fx[j], t = 1.0f - fy[j];
            float I1 = t * (u * R0[j].x + fx[j] * R0[j].y) + fy[j] * (u * R1[j].x + fx[j] * R1[j].y);
            float err = I0[j] - I1;
            bx += err * Ix[j];
            by += err * Iy[j];
        }
        bx = wredw(bx); by = wredw(by);
        vx += A * bx + Bv * by;
        vy += Bv * bx + D * by;
    }
    px += vx; py += vy;
}

__global__ __launch_bounds__(64) void lk_pair_kernel(const float* __restrict__ gray,
                                                     const float* __restrict__ sh,
                                                     const float* __restrict__ locs,
                                                     float* __restrict__ nextPts,
                                                     float* __restrict__ fbackPts,
                                                     float* __restrict__ backPts) {
    int g = blockIdx.x;
    int typ = g / (Bn * Pn);
    int r = g % (Bn * Pn);
    int b = r / Pn;
    int p = r % Pn;
    int lane = threadIdx.x;
    const float* G = gray + (size_t)b * Sn * HWi;
    const float* S = sh + (size_t)b * Sn * HWi;
    float dxs[5], dys[5];
    #pragma unroll
    for (int j = 0; j < 4; j++) {
        int k = lane + 64 * j;
        dxs[j] = (float)(k % 17 - 8);
        dys[j] = (float)(k / 17 - 8);
    }
    {
        int k4 = (lane < Kwin - 256) ? 256 + lane : 256;
        dxs[4] = (float)(k4 % 17 - 8);
        dys[4] = (float)(k4 / 17 - 8);
    }
    float s4w = (lane < Kwin - 256) ? 1.0f : 0.0f;
    auto LIDX = [&](int s) { return (((size_t)b * Sn + s) * Pn + p) * 2; };
    if (typ == 0) {
        float px = locs[LIDX(0)], py = locs[LIDX(0) + 1];
        if (lane == 0) { nextPts[LIDX(0)] = px; nextPts[LIDX(0) + 1] = py; }
        for (int s = 0; s < 7; s++) {
            lk_track_pair(G + s * HWi, S + s * HWi, G + (s + 1) * HWi, S + (s + 1) * HWi,
                          px, py, dxs, dys, s4w);
            if (lane == 0) { nextPts[LIDX(s + 1)] = px; nextPts[LIDX(s + 1) + 1] = py; }
        }
        if (lane == 0) { fbackPts[LIDX(7)] = px; fbackPts[LIDX(7) + 1] = py; }
        for (int i = 0; i < 7; i++) {
            lk_track_pair(G + (7 - i) * HWi, S + (7 - i) * HWi, G + (6 - i) * HWi, S + (6 - i) * HWi,
                          px, py, dxs, dys, s4w);
            if (lane == 0) { fbackPts[LIDX(6 - i)] = px; fbackPts[LIDX(6 - i) + 1] = py; }
        }
    } else {
        float px = locs[LIDX(7)], py = locs[LIDX(7) + 1];
        if (lane == 0) { backPts[LIDX(7)] = px; backPts[LIDX(7) + 1] = py; }
        for (int i = 0; i < 7; i++) {
            lk_track_pair(G + (7 - i) * HWi, S + (7 - i) * HWi, G + (6 - i) * HWi, S + (6 - i) * HWi,
                          px, py, dxs, dys, s4w);
            if (lane == 0) { backPts[LIDX(6 - i)] = px; backPts[LIDX(6 - i) + 1] = py; }
        }
    }
}

// ================= fallback tier 3: on-the-fly gray =================
__device__ inline float px_fly(const float* __restrict__ im, int idx) {
    return 0.299f * im[idx] + 0.587f * im[idx + HWi] + 0.114f * im[idx + 2 * HWi];
}

__device__ void lk_track_fly(const float* __restrict__ oldI, const float* __restrict__ newI,
                             float& px, float& py, const float* dxs, const float* dys,
                             float s4w) {
    const float XM = (float)(Wimg - 1.001);
    const float YM = (float)(Himg - 1.001);
    float I0[5], Ix[5], Iy[5], qx[5], qy[5];
    {
        float wx[5], wy[5];
        int am[5], a0[5], a1[5], ap[5], xm[5], x0[5], x1[5], xp[5];
        #pragma unroll
        for (int j = 0; j < 5; j++) {
            qx[j] = px + dxs[j]; qy[j] = py + dys[j];
            float x = fminf(fmaxf(qx[j], 0.0f), XM);
            float y = fminf(fmaxf(qy[j], 0.0f), YM);
            float x0f = floorf(x), y0f = floorf(y);
            wx[j] = x - x0f; wy[j] = y - y0f;
            int xi = (int)x0f, yi = (int)y0f;
            x0[j] = xi; x1[j] = min(xi + 1, Wimg - 1);
            xm[j] = max(xi - 1, 0); xp[j] = min(xi + 2, Wimg - 1);
            a0[j] = yi * Wimg;
            a1[j] = min(yi + 1, Himg - 1) * Wimg;
            am[j] = max(yi - 1, 0) * Wimg;
            ap[j] = min(yi + 2, Himg - 1) * Wimg;
        }
        #pragma unroll
        for (int j = 0; j < 5; j++) {
            float m0 = px_fly(oldI, am[j] + x0[j]), m1 = px_fly(oldI, am[j] + x1[j]);
            float c0m = px_fly(oldI, a0[j] + xm[j]), c00 = px_fly(oldI, a0[j] + x0[j]);
            float c01 = px_fly(oldI, a0[j] + x1[j]), c0p = px_fly(oldI, a0[j] + xp[j]);
            float c1m = px_fly(oldI, a1[j] + xm[j]), c10 = px_fly(oldI, a1[j] + x0[j]);
            float c11 = px_fly(oldI, a1[j] + x1[j]), c1p = px_fly(oldI, a1[j] + xp[j]);
            float p0 = px_fly(oldI, ap[j] + x0[j]), p1 = px_fly(oldI, ap[j] + x1[j]);
            float u = 1.0f - wx[j], t = 1.0f - wy[j];
            I0[j] = t * (u * c00 + wx[j] * c01) + wy[j] * (u * c10 + wx[j] * c11);
            Ix[j] = t * (u * 0.5f * (c01 - c0m) + wx[j] * 0.5f * (c0p - c00))
                  + wy[j] * (u * 0.5f * (c11 - c1m) + wx[j] * 0.5f * (c1p - c10));
            Iy[j] = t * (u * 0.5f * (c10 - m0) + wx[j] * 0.5f * (c11 - m1))
                  + wy[j] * (u * 0.5f * (p0 - c00) + wx[j] * 0.5f * (p1 - c01));
        }
        Ix[4] *= s4w; Iy[4] *= s4w;
    }
    float gxx = 0.f, gxy = 0.f, gyy = 0.f;
    #pragma unroll
    for (int j = 0; j < 5; j++) { gxx += Ix[j] * Ix[j]; gxy += Ix[j] * Iy[j]; gyy += Iy[j] * Iy[j]; }
    gxx = wredw(gxx); gxy = wredw(gxy); gyy = wredw(gyy);
    float det = gxx * gyy - gxy * gxy + 1e-6f;
    float A = gyy / det, Bv = -gxy / det, D = gxx / det;
    float vx = 0.f, vy = 0.f;
    for (int it = 0; it < STEPS; ++it) {
        float bx = 0.f, by = 0.f;
        #pragma unroll
        for (int j = 0; j < 5; j++) {
            float x = fminf(fmaxf(qx[j] + vx, 0.0f), XM);
            float y = fminf(fmaxf(qy[j] + vy, 0.0f), YM);
            float x0f = floorf(x), y0f = floorf(y);
            float fxx = x - x0f, fyy = y - y0f;
            int xi = (int)x0f, yi = (int)y0f;
            int ad = yi * Wimg + xi;
            int d1 = (xi < Wimg - 1) ? 1 : 0;
            int d2 = (yi < Himg - 1) ? Wimg : 0;
            float v00 = px_fly(newI, ad), v01 = px_fly(newI, ad + d1);
            float v10 = px_fly(newI, ad + d2), v11 = px_fly(newI, ad + d2 + d1);
            float u = 1.0f - fxx, t = 1.0f - fyy;
            float I1 = t * (u * v00 + fxx * v01) + fyy * (u * v10 + fxx * v11);
            float err = I0[j] - I1;
            bx += err * Ix[j];
            by += err * Iy[j];
        }
        bx = wredw(bx); by = wredw(by);
        vx += A * bx + Bv * by;
        vy += Bv * bx + D * by;
    }
    px += vx; py += vy;
}

__global__ __launch_bounds__(64) void lk_fly_kernel(const float* __restrict__ in,
                                                    const float* __restrict__ locs,
                                                    float* __restrict__ nextPts,
                                                    float* __restrict__ fbackPts,
                                                    float* __restrict__ backPts) {
    constexpr size_t FS = (size_t)3 * HWi;
    int g = blockIdx.x;
    int typ = g / (Bn * Pn);
    int r = g % (Bn * Pn);
    int b = r / Pn;
    int p = r % Pn;
    int lane = threadIdx.x;
    const float* G = in + (size_t)b * Sn * FS;
    float dxs[5], dys[5];
    #pragma unroll
    for (int j = 0; j < 4; j++) {
        int k = lane + 64 * j;
        dxs[j] = (float)(k % 17 - 8);
        dys[j] = (float)(k / 17 - 8);
    }
    {
        int k4 = (lane < Kwin - 256) ? 256 + lane : 256;
        dxs[4] = (float)(k4 % 17 - 8);
        dys[4] = (float)(k4 / 17 - 8);
    }
    float s4w = (lane < Kwin - 256) ? 1.0f : 0.0f;
    auto LIDX = [&](int s) { return (((size_t)b * Sn + s) * Pn + p) * 2; };
    if (typ == 0) {
        float px = locs[LIDX(0)], py = locs[LIDX(0) + 1];
        if (lane == 0) { nextPts[LIDX(0)] = px; nextPts[LIDX(0) + 1] = py; }
        for (int s = 0; s < 7; s++) {
            lk_track_fly(G + s * FS, G + (s + 1) * FS, px, py, dxs, dys, s4w);
            if (lane == 0) { nextPts[LIDX(s + 1)] = px; nextPts[LIDX(s + 1) + 1] = py; }
        }
        if (lane == 0) { fbackPts[LIDX(7)] = px; fbackPts[LIDX(7) + 1] = py; }
        for (int i = 0; i < 7; i++) {
            lk_track_fly(G + (7 - i) * FS, G + (6 - i) * FS, px, py, dxs, dys, s4w);
            if (lane == 0) { fbackPts[LIDX(6 - i)] = px; fbackPts[LIDX(6 - i) + 1] = py; }
        }
    } else {
        float px = locs[LIDX(7)], py = locs[LIDX(7) + 1];
        if (lane == 0) { backPts[LIDX(7)] = px; backPts[LIDX(7) + 1] = py; }
        for (int i = 0; i < 7; i++) {
            lk_track_fly(G + (7 - i) * FS, G + (6 - i) * FS, px, py, dxs, dys, s4w);
            if (lane == 0) { backPts[LIDX(6 - i)] = px; backPts[LIDX(6 - i) + 1] = py; }
        }
    }
}

// ---------------- launch ----------------
extern "C" void kernel_launch(void* const* d_in, const int* in_sizes, int n_in,
                              void* d_out, int out_size, void* d_ws, size_t ws_size,
                              hipStream_t stream) {
    const float* inputs = (const float*)d_in[0];
    const float* Wdet = (const float*)d_in[1];
    const float* bdet = (const float*)d_in[2];
    float* out = (float*)d_out;

    const size_t N_hm = (size_t)Bn * Sn * Pn * HD * WD;   // 8,912,896
    const size_t N_pts = (size_t)Bn * Sn * Pn * 2;        // 4352
    float* hm = out;
    float* locs = out + N_hm;
    float* scos = locs + N_pts;
    float* nextPts = scos + (size_t)Bn * Sn * Pn;
    float* fbackPts = nextPts + N_pts;
    float* backPts = fbackPts + N_pts;

    conv_kernel<<<NIMG * 64, 256, 0, stream>>>(inputs, Wdet, bdet, hm);
    smax_kernel<<<NIMG * Pn, 256, 0, stream>>>(hm, locs, scos);

    const size_t p2_bytes = (size_t)2 * NIMG * P2FR * sizeof(float2);   // ~33.7 MB
    const size_t gray_elems = (size_t)NIMG * HWi;
    if (ws_size >= p2_bytes) {
        float2* P2r = (float2*)d_ws;
        float2* P2rs = P2r + (size_t)NIMG * P2FR;
        grayP2_kernel<<<NIMG * 33, 256, 0, stream>>>(inputs, P2r, P2rs);
        lk_p2_kernel<<<2 * Bn * Pn, 64, 0, stream>>>(P2r, locs, nextPts, fbackPts, backPts);
    } else if (ws_size >= 2 * gray_elems * sizeof(float)) {
        float* gray = (float*)d_ws;
        float* sh = gray + gray_elems;
        gray2_kernel<<<(NIMG * HWi / 4 + 255) / 256, 256, 0, stream>>>(inputs, gray, sh);
        lk_pair_kernel<<<2 * Bn * Pn, 64, 0, stream>>>(gray, sh, locs, nextPts, fbackPts, backPts);
    } else {
        lk_fly_kernel<<<2 * Bn * Pn, 64, 0, stream>>>(inputs, locs, nextPts, fbackPts, backPts);
    }
}

// Round 11
// 112.038 us; speedup vs baseline: 1.1220x; 1.0112x over previous
//
#include <hip/hip_runtime.h>
#include <math.h>

// ---------------- problem constants ----------------
namespace {
constexpr int Bn = 4, Sn = 8, Cn = 3, Himg = 256, Wimg = 256;
constexpr int Pn = 68, DS = 4, WIN = 8, STEPS = 10;
constexpr int HWi = Himg * Wimg;            // 65536
constexpr int NIMG = Bn * Sn;               // 32
constexpr int HD = Himg / DS, WD = Wimg / DS; // 64 x 64
constexpr int Kwin = (2 * WIN + 1) * (2 * WIN + 1); // 289
// row-pair image: P2r[k][x] = (gray[max(k-1,0)][x], gray[min(k,255)][x]), k=0..256
constexpr int P2ROWS = 257;
constexpr int P2FR = P2ROWS * 256;           // 65792 float2 per frame
constexpr int NSHIFT = NIMG * P2FR;          // offset from P2r to P2rs (float2 units)
}

// ---------------- MEGA: conv (3x3 s4) + gray + P2r/P2rs build ----------------
// Block (n,oy): stages input rows clamp(4oy-1 .. 4oy+3), conv from rows 1..3,
// gray rows 0..4 -> P2 rows 4oy..4oy+3 (+ row 256 when oy==63).
__global__ __launch_bounds__(256) void mega_kernel(const float* __restrict__ x,
                                                   const float* __restrict__ Wdet,
                                                   const float* __restrict__ bdet,
                                                   float* __restrict__ hm,
                                                   float2* __restrict__ P2r,
                                                   float2* __restrict__ P2rs) {
    __shared__ float wsh[Pn * 27];
    __shared__ float bsh[Pn];
    __shared__ float insh[3][5][Wimg];
    __shared__ float grow[5][257];
    int n = blockIdx.x >> 6;
    int oy = blockIdx.x & 63;
    int tid = threadIdx.x;
    for (int t = tid; t < Pn * 27; t += 256) wsh[t] = Wdet[t];
    if (tid < Pn) bsh[tid] = bdet[tid];
    for (int t = tid; t < 3 * 5 * Wimg; t += 256) {
        int c = t / (5 * Wimg);
        int rem = t % (5 * Wimg);
        int r = rem / Wimg;
        int col = rem % Wimg;
        int gr = min(max(4 * oy - 1 + r, 0), 255);
        insh[c][r][col] = x[(size_t)n * 3 * HWi + (size_t)c * HWi + gr * Wimg + col];
    }
    __syncthreads();
    // ---- conv part (rows 1..3 of the stage) ----
    int ox = tid & 63;
    int wid = tid >> 6;
    float in_reg[27];
    #pragma unroll
    for (int c = 0; c < 3; c++)
        #pragma unroll
        for (int ky = 0; ky < 3; ky++)
            #pragma unroll
            for (int kx = 0; kx < 3; kx++)
                in_reg[c * 9 + ky * 3 + kx] = insh[c][1 + ky][ox * 4 + kx];
    #pragma unroll
    for (int i = 0; i < 17; i++) {
        int p = wid + i * 4;
        const float* w = &wsh[p * 27];
        float acc = bsh[p];
        #pragma unroll
        for (int j = 0; j < 27; j++) acc += w[j] * in_reg[j];
        hm[(size_t)n * Pn * 4096 + (size_t)p * 4096 + oy * 64 + ox] = acc;
    }
    // ---- gray rows 0..4 ----
    #pragma unroll
    for (int r = 0; r < 5; r++)
        grow[r][tid] = 0.299f * insh[0][r][tid] + 0.587f * insh[1][r][tid] + 0.114f * insh[2][r][tid];
    if (tid < 5) grow[tid][256] = grow[tid][255];   // pad col (ps cols 254/255 never read)
    __syncthreads();
    // ---- P2 rows 4oy .. 4oy+3 (+256 at oy=63) ----
    float2* pr = P2r + (size_t)n * P2FR;
    float2* ps = P2rs + (size_t)n * P2FR;
    #pragma unroll
    for (int j = 0; j < 4; j++) {
        int k = 4 * oy + j;
        pr[k * 256 + tid] = make_float2(grow[j][tid], grow[j + 1][tid]);
        ps[k * 256 + tid] = make_float2(grow[j][tid + 1], grow[j + 1][tid + 1]);
    }
    if (oy == 63) {
        pr[256 * 256 + tid] = make_float2(grow[4][tid], grow[4][tid]);
        ps[256 * 256 + tid] = make_float2(grow[4][tid + 1], grow[4][tid + 1]);
    }
}

// ---------------- plain conv (fallback tiers) ----------------
__global__ __launch_bounds__(256) void conv_kernel(const float* __restrict__ x,
                                                   const float* __restrict__ Wdet,
                                                   const float* __restrict__ bdet,
                                                   float* __restrict__ hm) {
    __shared__ float wsh[Pn * 27];
    __shared__ float bsh[Pn];
    __shared__ float insh[3][3][Wimg];
    int n = blockIdx.x >> 6;
    int oy = blockIdx.x & 63;
    int tid = threadIdx.x;
    for (int t = tid; t < Pn * 27; t += 256) wsh[t] = Wdet[t];
    if (tid < Pn) bsh[tid] = bdet[tid];
    for (int t = tid; t < 3 * 3 * Wimg; t += 256) {
        int c = t / (3 * Wimg);
        int r = (t / Wimg) % 3;
        int col = t % Wimg;
        insh[c][r][col] = x[(size_t)n * 3 * HWi + (size_t)c * HWi + (oy * 4 + r) * Wimg + col];
    }
    __syncthreads();
    int ox = tid & 63;
    int wid = tid >> 6;
    float in_reg[27];
    #pragma unroll
    for (int c = 0; c < 3; c++)
        #pragma unroll
        for (int ky = 0; ky < 3; ky++)
            #pragma unroll
            for (int kx = 0; kx < 3; kx++)
                in_reg[c * 9 + ky * 3 + kx] = insh[c][ky][ox * 4 + kx];
    #pragma unroll
    for (int i = 0; i < 17; i++) {
        int p = wid + i * 4;
        const float* w = &wsh[p * 27];
        float acc = bsh[p];
        #pragma unroll
        for (int j = 0; j < 27; j++) acc += w[j] * in_reg[j];
        hm[(size_t)n * Pn * 4096 + (size_t)p * 4096 + oy * 64 + ox] = acc;
    }
}

// ---------------- softmax / soft-argmax / scores ----------------
__global__ __launch_bounds__(256) void smax_kernel(const float* __restrict__ hm,
                                                   float* __restrict__ locs,
                                                   float* __restrict__ scos) {
    int row = blockIdx.x;   // n*Pn + p
    const float4* r = (const float4*)(hm + (size_t)row * 4096);
    int tid = threadIdx.x;
    float v[16];
    #pragma unroll
    for (int j = 0; j < 4; j++) {
        float4 q = r[tid + 256 * j];
        v[4 * j + 0] = q.x; v[4 * j + 1] = q.y; v[4 * j + 2] = q.z; v[4 * j + 3] = q.w;
    }
    float m = v[0];
    #pragma unroll
    for (int i = 1; i < 16; i++) m = fmaxf(m, v[i]);
    __shared__ float redm[4];
    #pragma unroll
    for (int o = 32; o; o >>= 1) m = fmaxf(m, __shfl_xor(m, o, 64));
    int wid = tid >> 6, lane = tid & 63;
    if (lane == 0) redm[wid] = m;
    __syncthreads();
    m = fmaxf(fmaxf(redm[0], redm[1]), fmaxf(redm[2], redm[3]));
    float s = 0.f, sx = 0.f, sy = 0.f;
    #pragma unroll
    for (int j = 0; j < 4; j++) {
        #pragma unroll
        for (int q = 0; q < 4; q++) {
            int e = (tid + 256 * j) * 4 + q;
            float ev = expf(v[4 * j + q] - m);
            s += ev;
            sx += ev * (float)(e & 63);
            sy += ev * (float)(e >> 6);
        }
    }
    #pragma unroll
    for (int o = 32; o; o >>= 1) {
        s  += __shfl_xor(s, o, 64);
        sx += __shfl_xor(sx, o, 64);
        sy += __shfl_xor(sy, o, 64);
    }
    __shared__ float reds[3][4];
    if (lane == 0) { reds[0][wid] = s; reds[1][wid] = sx; reds[2][wid] = sy; }
    __syncthreads();
    if (tid == 0) {
        float S_ = reds[0][0] + reds[0][1] + reds[0][2] + reds[0][3];
        float SX = reds[1][0] + reds[1][1] + reds[1][2] + reds[1][3];
        float SY = reds[2][0] + reds[2][1] + reds[2][2] + reds[2][3];
        locs[(size_t)row * 2 + 0] = SX / S_ * 4.0f;
        locs[(size_t)row * 2 + 1] = SY / S_ * 4.0f;
        scos[row] = m;
    }
}

// ---------------- DPP wave64 sum reduction (VALU-only) ----------------
template <int CTRL>
__device__ inline float dpp_add(float v) {
    int t = __builtin_amdgcn_update_dpp(0, __builtin_bit_cast(int, v), CTRL, 0xF, 0xF, true);
    return v + __builtin_bit_cast(float, t);
}

__device__ inline float wredw(float v) {
    v = dpp_add<0x111>(v);   // row_shr:1
    v = dpp_add<0x112>(v);   // row_shr:2
    v = dpp_add<0x114>(v);   // row_shr:4
    v = dpp_add<0x118>(v);   // row_shr:8
    v = dpp_add<0x142>(v);   // row_bcast:15
    v = dpp_add<0x143>(v);   // row_bcast:31
    int s = __builtin_amdgcn_readlane(__builtin_bit_cast(int, v), 63);
    return __builtin_bit_cast(float, s);
}

// ---------------- LK track step on row-pair images (1 wave/chain) ----------------
// Iter-0 gathers (v=0 => positions == template positions) are issued WITH the
// template loads so their latency hides under gradient math + G reduce. Exact.
__device__ void lk_track_p2(const float2* __restrict__ Po, const float2* __restrict__ Pn,
                            float& px, float& py, const float* dxs, const float* dys,
                            float s4w) {
    const float XM = (float)(Wimg - 1.001);
    const float YM = (float)(Himg - 1.001);
    float I0[5], Ix[5], Iy[5], qx[5], qy[5];
    float wx[5], wy[5];
    float4 Q0[5];
    // ---- template phase + iter-0 prefetch ----
    {
        int idx[5], sb[5], xm[5], xp[5], id0[5];
        #pragma unroll
        for (int j = 0; j < 5; j++) {
            qx[j] = px + dxs[j];
            qy[j] = py + dys[j];
            float x = fminf(fmaxf(qx[j], 0.0f), XM);
            float y = fminf(fmaxf(qy[j], 0.0f), YM);
            float xf = floorf(x), yf = floorf(y);
            wx[j] = x - xf; wy[j] = y - yf;
            int xi = (int)xf, yi = (int)yf;
            int col = xi & ~1;
            int sel = (xi & 1) ? NSHIFT : 0;
            idx[j] = yi * 256 + col + sel;
            sb[j] = (yi + 1) * 256;
            id0[j] = sb[j] + col + sel;
            xm[j] = max(xi - 1, 0);
            xp[j] = min(xi + 2, Wimg - 1);
        }
        float4 A[5], B[5];
        float2 S1[5], S2[5];
        #pragma unroll
        for (int j = 0; j < 5; j++) {
            A[j] = *reinterpret_cast<const float4*>(Po + idx[j]);         // (m0,c00,m1,c01)
            B[j] = *reinterpret_cast<const float4*>(Po + idx[j] + 512);   // (c10,p0,c11,p1)
            S1[j] = Po[sb[j] + xm[j]];                                    // (c0m,c1m)
            S2[j] = Po[sb[j] + xp[j]];                                    // (c0p,c1p)
            Q0[j] = *reinterpret_cast<const float4*>(Pn + id0[j]);        // iter-0 (v00,v10,v01,v11)
        }
        #pragma unroll
        for (int j = 0; j < 5; j++) {
            float m0 = A[j].x, c00 = A[j].y, m1 = A[j].z, c01 = A[j].w;
            float c10 = B[j].x, p0 = B[j].y, c11 = B[j].z, p1 = B[j].w;
            float c0m = S1[j].x, c1m = S1[j].y, c0p = S2[j].x, c1p = S2[j].y;
            float u = 1.0f - wx[j], t = 1.0f - wy[j];
            I0[j] = t * (u * c00 + wx[j] * c01) + wy[j] * (u * c10 + wx[j] * c11);
            float gx00 = 0.5f * (c01 - c0m);
            float gx01 = 0.5f * (c0p - c00);
            float gx10 = 0.5f * (c11 - c1m);
            float gx11 = 0.5f * (c1p - c10);
            Ix[j] = t * (u * gx00 + wx[j] * gx01) + wy[j] * (u * gx10 + wx[j] * gx11);
            float gy00 = 0.5f * (c10 - m0);
            float gy01 = 0.5f * (c11 - m1);
            float gy10 = 0.5f * (p0 - c00);
            float gy11 = 0.5f * (p1 - c01);
            Iy[j] = t * (u * gy00 + wx[j] * gy01) + wy[j] * (u * gy10 + wx[j] * gy11);
        }
        Ix[4] *= s4w;
        Iy[4] *= s4w;
    }
    float gxx = 0.f, gxy = 0.f, gyy = 0.f;
    #pragma unroll
    for (int j = 0; j < 5; j++) { gxx += Ix[j] * Ix[j]; gxy += Ix[j] * Iy[j]; gyy += Iy[j] * Iy[j]; }
    gxx = wredw(gxx); gxy = wredw(gxy); gyy = wredw(gyy);
    float det = gxx * gyy - gxy * gxy + 1e-6f;
    float A = gyy / det, Bv = -gxy / det, D = gxx / det;  // Ginv
    float vx = 0.f, vy = 0.f;
    // ---- iter 0 from prefetched Q0 (fx==wx, fy==wy bitwise) ----
    {
        float bx = 0.f, by = 0.f;
        #pragma unroll
        for (int j = 0; j < 5; j++) {
            float u = 1.0f - wx[j], t = 1.0f - wy[j];
            float I1 = t * (u * Q0[j].x + wx[j] * Q0[j].z) + wy[j] * (u * Q0[j].y + wx[j] * Q0[j].w);
            float err = I0[j] - I1;
            bx += err * Ix[j];
            by += err * Iy[j];
        }
        bx = wredw(bx); by = wredw(by);
        vx += A * bx + Bv * by;
        vy += Bv * bx + D * by;
    }
    // ---- iters 1..9: 5 dwordx4 gathers per iter ----
    for (int it = 1; it < STEPS; ++it) {
        float fx[5], fy[5];
        int id[5];
        #pragma unroll
        for (int j = 0; j < 5; j++) {
            float x = fminf(fmaxf(qx[j] + vx, 0.0f), XM);
            float y = fminf(fmaxf(qy[j] + vy, 0.0f), YM);
            float xf = floorf(x), yf = floorf(y);
            fx[j] = x - xf; fy[j] = y - yf;
            int xi = (int)xf, yi = (int)yf;
            id[j] = (yi + 1) * 256 + (xi & ~1) + ((xi & 1) ? NSHIFT : 0);
        }
        float4 Q[5];
        #pragma unroll
        for (int j = 0; j < 5; j++) Q[j] = *reinterpret_cast<const float4*>(Pn + id[j]);
        float bx = 0.f, by = 0.f;
        #pragma unroll
        for (int j = 0; j < 5; j++) {
            float u = 1.0f - fx[j], t = 1.0f - fy[j];
            float I1 = t * (u * Q[j].x + fx[j] * Q[j].z) + fy[j] * (u * Q[j].y + fx[j] * Q[j].w);
            float err = I0[j] - I1;
            bx += err * Ix[j];
            by += err * Iy[j];
        }
        bx = wredw(bx); by = wredw(by);
        vx += A * bx + Bv * by;
        vy += Bv * bx + D * by;
    }
    px += vx; py += vy;
}

__global__ __launch_bounds__(64) void lk_p2_kernel(const float2* __restrict__ P2r,
                                                   const float* __restrict__ locs,
                                                   float* __restrict__ nextPts,
                                                   float* __restrict__ fbackPts,
                                                   float* __restrict__ backPts) {
    int g = blockIdx.x;
    int typ = g / (Bn * Pn);
    int r = g % (Bn * Pn);
    int b = r / Pn;
    int p = r % Pn;
    int lane = threadIdx.x;
    const float2* F = P2r + (size_t)b * Sn * P2FR;
    float dxs[5], dys[5];
    #pragma unroll
    for (int j = 0; j < 4; j++) {
        int k = lane + 64 * j;
        dxs[j] = (float)(k % 17 - 8);
        dys[j] = (float)(k / 17 - 8);
    }
    {
        int k4 = (lane < Kwin - 256) ? 256 + lane : 256;
        dxs[4] = (float)(k4 % 17 - 8);
        dys[4] = (float)(k4 / 17 - 8);
    }
    float s4w = (lane < Kwin - 256) ? 1.0f : 0.0f;
    auto LIDX = [&](int s) { return (((size_t)b * Sn + s) * Pn + p) * 2; };
    if (typ == 0) {
        float px = locs[LIDX(0)], py = locs[LIDX(0) + 1];
        if (lane == 0) { nextPts[LIDX(0)] = px; nextPts[LIDX(0) + 1] = py; }
        for (int s = 0; s < 7; s++) {
            lk_track_p2(F + s * P2FR, F + (s + 1) * P2FR, px, py, dxs, dys, s4w);
            if (lane == 0) { nextPts[LIDX(s + 1)] = px; nextPts[LIDX(s + 1) + 1] = py; }
        }
        if (lane == 0) { fbackPts[LIDX(7)] = px; fbackPts[LIDX(7) + 1] = py; }
        for (int i = 0; i < 7; i++) {
            lk_track_p2(F + (7 - i) * P2FR, F + (6 - i) * P2FR, px, py, dxs, dys, s4w);
            if (lane == 0) { fbackPts[LIDX(6 - i)] = px; fbackPts[LIDX(6 - i) + 1] = py; }
        }
    } else {
        float px = locs[LIDX(7)], py = locs[LIDX(7) + 1];
        if (lane == 0) { backPts[LIDX(7)] = px; backPts[LIDX(7) + 1] = py; }
        for (int i = 0; i < 7; i++) {
            lk_track_p2(F + (7 - i) * P2FR, F + (6 - i) * P2FR, px, py, dxs, dys, s4w);
            if (lane == 0) { backPts[LIDX(6 - i)] = px; backPts[LIDX(6 - i) + 1] = py; }
        }
    }
}

// ================= fallback tier 2: pair path (ws >= 16.8 MB) =================
__global__ __launch_bounds__(256) void gray2_kernel(const float* __restrict__ in,
                                                    float* __restrict__ gray,
                                                    float* __restrict__ sh) {
    int idx = blockIdx.x * blockDim.x + threadIdx.x;
    int total = NIMG * HWi / 4;
    if (idx >= total) return;
    int img = idx / (HWi / 4);
    int off = idx % (HWi / 4);
    const float* base = in + (size_t)img * 3 * HWi;
    float4 c0 = ((const float4*)(base))[off];
    float4 c1 = ((const float4*)(base + HWi))[off];
    float4 c2 = ((const float4*)(base + 2 * HWi))[off];
    float4 g;
    g.x = 0.299f * c0.x + 0.587f * c1.x + 0.114f * c2.x;
    g.y = 0.299f * c0.y + 0.587f * c1.y + 0.114f * c2.y;
    g.z = 0.299f * c0.z + 0.587f * c1.z + 0.114f * c2.z;
    g.w = 0.299f * c0.w + 0.587f * c1.w + 0.114f * c2.w;
    float gn = 0.f;
    int gi = idx * 4 + 4;
    if (gi < NIMG * HWi) {
        int i2 = gi / HWi;
        int o2 = gi % HWi;
        const float* b2 = in + (size_t)i2 * 3 * HWi;
        gn = 0.299f * b2[o2] + 0.587f * b2[o2 + HWi] + 0.114f * b2[o2 + 2 * HWi];
    }
    ((float4*)(gray + (size_t)img * HWi))[off] = g;
    float4 s;
    s.x = g.y; s.y = g.z; s.z = g.w; s.w = gn;
    ((float4*)(sh + (size_t)img * HWi))[off] = s;
}

__device__ void lk_track_pair(const float* __restrict__ oldI, const float* __restrict__ oldS,
                              const float* __restrict__ newI, const float* __restrict__ newS,
                              float& px, float& py, const float* dxs, const float* dys,
                              float s4w) {
    const float XM = (float)(Wimg - 1.001);
    const float YM = (float)(Himg - 1.001);
    float I0[5], Ix[5], Iy[5], qx[5], qy[5];
    {
        float wx[5], wy[5];
        const float* pb[5];
        int xe[5], am[5], a0[5], a1[5], ap[5], xm[5], xp[5];
        #pragma unroll
        for (int j = 0; j < 5; j++) {
            qx[j] = px + dxs[j];
            qy[j] = py + dys[j];
            float x = fminf(fmaxf(qx[j], 0.0f), XM);
            float y = fminf(fmaxf(qy[j], 0.0f), YM);
            float x0f = floorf(x), y0f = floorf(y);
            wx[j] = x - x0f; wy[j] = y - y0f;
            int xi = (int)x0f, yi = (int)y0f;
            xe[j] = xi & ~1;
            pb[j] = (xi & 1) ? oldS : oldI;
            xm[j] = max(xi - 1, 0);
            xp[j] = min(xi + 2, Wimg - 1);
            a0[j] = yi * Wimg;
            a1[j] = a0[j] + Wimg;
            am[j] = max(yi - 1, 0) * Wimg;
            ap[j] = min(yi + 2, Himg - 1) * Wimg;
        }
        float2 Pm[5], P0[5], P1[5], Pp[5];
        float c0m[5], c0p[5], c1m[5], c1p[5];
        #pragma unroll
        for (int j = 0; j < 5; j++) {
            Pm[j] = *(const float2*)(pb[j] + am[j] + xe[j]);
            P0[j] = *(const float2*)(pb[j] + a0[j] + xe[j]);
            P1[j] = *(const float2*)(pb[j] + a1[j] + xe[j]);
            Pp[j] = *(const float2*)(pb[j] + ap[j] + xe[j]);
            c0m[j] = oldI[a0[j] + xm[j]];
            c0p[j] = oldI[a0[j] + xp[j]];
            c1m[j] = oldI[a1[j] + xm[j]];
            c1p[j] = oldI[a1[j] + xp[j]];
        }
        #pragma unroll
        for (int j = 0; j < 5; j++) {
            float m0 = Pm[j].x, m1 = Pm[j].y;
            float c00 = P0[j].x, c01 = P0[j].y;
            float c10 = P1[j].x, c11 = P1[j].y;
            float p0 = Pp[j].x, p1 = Pp[j].y;
            float u = 1.0f - wx[j], t = 1.0f - wy[j];
            I0[j] = t * (u * c00 + wx[j] * c01) + wy[j] * (u * c10 + wx[j] * c11);
            float gx00 = 0.5f * (c01 - c0m[j]);
            float gx01 = 0.5f * (c0p[j] - c00);
            float gx10 = 0.5f * (c11 - c1m[j]);
            float gx11 = 0.5f * (c1p[j] - c10);
            Ix[j] = t * (u * gx00 + wx[j] * gx01) + wy[j] * (u * gx10 + wx[j] * gx11);
            float gy00 = 0.5f * (c10 - m0);
            float gy01 = 0.5f * (c11 - m1);
            float gy10 = 0.5f * (p0 - c00);
            float gy11 = 0.5f * (p1 - c01);
            Iy[j] = t * (u * gy00 + wx[j] * gy01) + wy[j] * (u * gy10 + wx[j] * gy11);
        }
        Ix[4] *= s4w;
        Iy[4] *= s4w;
    }
    float gxx = 0.f, gxy = 0.f, gyy = 0.f;
    #pragma unroll
    for (int j = 0; j < 5; j++) { gxx += Ix[j] * Ix[j]; gxy += Ix[j] * Iy[j]; gyy += Iy[j] * Iy[j]; }
    gxx = wredw(gxx); gxy = wredw(gxy); gyy = wredw(gyy);
    float det = gxx * gyy - gxy * gxy + 1e-6f;
    float A = gyy / det, Bv = -gxy / det, D = gxx / det;
    float vx = 0.f, vy = 0.f;
    for (int it = 0; it < STEPS; ++it) {
        float fx[5], fy[5];
        const float* pb[5];
        int aa[5];
        #pragma unroll
        for (int j = 0; j < 5; j++) {
            float x = fminf(fmaxf(qx[j] + vx, 0.0f), XM);
            float y = fminf(fmaxf(qy[j] + vy, 0.0f), YM);
            float x0f = floorf(x), y0f = floorf(y);
            fx[j] = x - x0f; fy[j] = y - y0f;
            int xi = (int)x0f, yi = (int)y0f;
            pb[j] = (xi & 1) ? newS : newI;
            aa[j] = yi * Wimg + (xi & ~1);
        }
        float2 R0[5], R1[5];
        #pragma unroll
        for (int j = 0; j < 5; j++) {
            R0[j] = *(const float2*)(pb[j] + aa[j]);
            R1[j] = *(const float2*)(pb[j] + aa[j] + Wimg);
        }
        float bx = 0.f, by = 0.f;
        #pragma unroll
        for (int j = 0; j < 5; j++) {
            float u = 1.0f - fx[j], t = 1.0f - fy[j];
            float I1 = t * (u * R0[j].x + fx[j] * R0[j].y) + fy[j] * (u * R1[j].x + fx[j] * R1[j].y);
            float err = I0[j] - I1;
            bx += err * Ix[j];
            by += err * Iy[j];
        }
        bx = wredw(bx); by = wredw(by);
        vx += A * bx + Bv * by;
        vy += Bv * bx + D * by;
    }
    px += vx; py += vy;
}

__global__ __launch_bounds__(64) void lk_pair_kernel(const float* __restrict__ gray,
                                                     const float* __restrict__ sh,
                                                     const float* __restrict__ locs,
                                                     float* __restrict__ nextPts,
                                                     float* __restrict__ fbackPts,
                                                     float* __restrict__ backPts) {
    int g = blockIdx.x;
    int typ = g / (Bn * Pn);
    int r = g % (Bn * Pn);
    int b = r / Pn;
    int p = r % Pn;
    int lane = threadIdx.x;
    const float* G = gray + (size_t)b * Sn * HWi;
    const float* S = sh + (size_t)b * Sn * HWi;
    float dxs[5], dys[5];
    #pragma unroll
    for (int j = 0; j < 4; j++) {
        int k = lane + 64 * j;
        dxs[j] = (float)(k % 17 - 8);
        dys[j] = (float)(k / 17 - 8);
    }
    {
        int k4 = (lane < Kwin - 256) ? 256 + lane : 256;
        dxs[4] = (float)(k4 % 17 - 8);
        dys[4] = (float)(k4 / 17 - 8);
    }
    float s4w = (lane < Kwin - 256) ? 1.0f : 0.0f;
    auto LIDX = [&](int s) { return (((size_t)b * Sn + s) * Pn + p) * 2; };
    if (typ == 0) {
        float px = locs[LIDX(0)], py = locs[LIDX(0) + 1];
        if (lane == 0) { nextPts[LIDX(0)] = px; nextPts[LIDX(0) + 1] = py; }
        for (int s = 0; s < 7; s++) {
            lk_track_pair(G + s * HWi, S + s * HWi, G + (s + 1) * HWi, S + (s + 1) * HWi,
                          px, py, dxs, dys, s4w);
            if (lane == 0) { nextPts[LIDX(s + 1)] = px; nextPts[LIDX(s + 1) + 1] = py; }
        }
        if (lane == 0) { fbackPts[LIDX(7)] = px; fbackPts[LIDX(7) + 1] = py; }
        for (int i = 0; i < 7; i++) {
            lk_track_pair(G + (7 - i) * HWi, S + (7 - i) * HWi, G + (6 - i) * HWi, S + (6 - i) * HWi,
                          px, py, dxs, dys, s4w);
            if (lane == 0) { fbackPts[LIDX(6 - i)] = px; fbackPts[LIDX(6 - i) + 1] = py; }
        }
    } else {
        float px = locs[LIDX(7)], py = locs[LIDX(7) + 1];
        if (lane == 0) { backPts[LIDX(7)] = px; backPts[LIDX(7) + 1] = py; }
        for (int i = 0; i < 7; i++) {
            lk_track_pair(G + (7 - i) * HWi, S + (7 - i) * HWi, G + (6 - i) * HWi, S + (6 - i) * HWi,
                          px, py, dxs, dys, s4w);
            if (lane == 0) { backPts[LIDX(6 - i)] = px; backPts[LIDX(6 - i) + 1] = py; }
        }
    }
}

// ================= fallback tier 3: on-the-fly gray =================
__device__ inline float px_fly(const float* __restrict__ im, int idx) {
    return 0.299f * im[idx] + 0.587f * im[idx + HWi] + 0.114f * im[idx + 2 * HWi];
}

__device__ void lk_track_fly(const float* __restrict__ oldI, const float* __restrict__ newI,
                             float& px, float& py, const float* dxs, const float* dys,
                             float s4w) {
    const float XM = (float)(Wimg - 1.001);
    const float YM = (float)(Himg - 1.001);
    float I0[5], Ix[5], Iy[5], qx[5], qy[5];
    {
        float wx[5], wy[5];
        int am[5], a0[5], a1[5], ap[5], xm[5], x0[5], x1[5], xp[5];
        #pragma unroll
        for (int j = 0; j < 5; j++) {
            qx[j] = px + dxs[j]; qy[j] = py + dys[j];
            float x = fminf(fmaxf(qx[j], 0.0f), XM);
            float y = fminf(fmaxf(qy[j], 0.0f), YM);
            float x0f = floorf(x), y0f = floorf(y);
            wx[j] = x - x0f; wy[j] = y - y0f;
            int xi = (int)x0f, yi = (int)y0f;
            x0[j] = xi; x1[j] = min(xi + 1, Wimg - 1);
            xm[j] = max(xi - 1, 0); xp[j] = min(xi + 2, Wimg - 1);
            a0[j] = yi * Wimg;
            a1[j] = min(yi + 1, Himg - 1) * Wimg;
            am[j] = max(yi - 1, 0) * Wimg;
            ap[j] = min(yi + 2, Himg - 1) * Wimg;
        }
        #pragma unroll
        for (int j = 0; j < 5; j++) {
            float m0 = px_fly(oldI, am[j] + x0[j]), m1 = px_fly(oldI, am[j] + x1[j]);
            float c0m = px_fly(oldI, a0[j] + xm[j]), c00 = px_fly(oldI, a0[j] + x0[j]);
            float c01 = px_fly(oldI, a0[j] + x1[j]), c0p = px_fly(oldI, a0[j] + xp[j]);
            float c1m = px_fly(oldI, a1[j] + xm[j]), c10 = px_fly(oldI, a1[j] + x0[j]);
            float c11 = px_fly(oldI, a1[j] + x1[j]), c1p = px_fly(oldI, a1[j] + xp[j]);
            float p0 = px_fly(oldI, ap[j] + x0[j]), p1 = px_fly(oldI, ap[j] + x1[j]);
            float u = 1.0f - wx[j], t = 1.0f - wy[j];
            I0[j] = t * (u * c00 + wx[j] * c01) + wy[j] * (u * c10 + wx[j] * c11);
            Ix[j] = t * (u * 0.5f * (c01 - c0m) + wx[j] * 0.5f * (c0p - c00))
                  + wy[j] * (u * 0.5f * (c11 - c1m) + wx[j] * 0.5f * (c1p - c10));
            Iy[j] = t * (u * 0.5f * (c10 - m0) + wx[j] * 0.5f * (c11 - m1))
                  + wy[j] * (u * 0.5f * (p0 - c00) + wx[j] * 0.5f * (p1 - c01));
        }
        Ix[4] *= s4w; Iy[4] *= s4w;
    }
    float gxx = 0.f, gxy = 0.f, gyy = 0.f;
    #pragma unroll
    for (int j = 0; j < 5; j++) { gxx += Ix[j] * Ix[j]; gxy += Ix[j] * Iy[j]; gyy += Iy[j] * Iy[j]; }
    gxx = wredw(gxx); gxy = wredw(gxy); gyy = wredw(gyy);
    float det = gxx * gyy - gxy * gxy + 1e-6f;
    float A = gyy / det, Bv = -gxy / det, D = gxx / det;
    float vx = 0.f, vy = 0.f;
    for (int it = 0; it < STEPS; ++it) {
        float bx = 0.f, by = 0.f;
        #pragma unroll
        for (int j = 0; j < 5; j++) {
            float x = fminf(fmaxf(qx[j] + vx, 0.0f), XM);
            float y = fminf(fmaxf(qy[j] + vy, 0.0f), YM);
            float x0f = floorf(x), y0f = floorf(y);
            float fxx = x - x0f, fyy = y - y0f;
            int xi = (int)x0f, yi = (int)y0f;
            int ad = yi * Wimg + xi;
            int d1 = (xi < Wimg - 1) ? 1 : 0;
            int d2 = (yi < Himg - 1) ? Wimg : 0;
            float v00 = px_fly(newI, ad), v01 = px_fly(newI, ad + d1);
            float v10 = px_fly(newI, ad + d2), v11 = px_fly(newI, ad + d2 + d1);
            float u = 1.0f - fxx, t = 1.0f - fyy;
            float I1 = t * (u * v00 + fxx * v01) + fyy * (u * v10 + fxx * v11);
            float err = I0[j] - I1;
            bx += err * Ix[j];
            by += err * Iy[j];
        }
        bx = wredw(bx); by = wredw(by);
        vx += A * bx + Bv * by;
        vy += Bv * bx + D * by;
    }
    px += vx; py += vy;
}

__global__ __launch_bounds__(64) void lk_fly_kernel(const float* __restrict__ in,
                                                    const float* __restrict__ locs,
                                                    float* __restrict__ nextPts,
                                                    float* __restrict__ fbackPts,
                                                    float* __restrict__ backPts) {
    constexpr size_t FS = (size_t)3 * HWi;
    int g = blockIdx.x;
    int typ = g / (Bn * Pn);
    int r = g % (Bn * Pn);
    int b = r / Pn;
    int p = r % Pn;
    int lane = threadIdx.x;
    const float* G = in + (size_t)b * Sn * FS;
    float dxs[5], dys[5];
    #pragma unroll
    for (int j = 0; j < 4; j++) {
        int k = lane + 64 * j;
        dxs[j] = (float)(k % 17 - 8);
        dys[j] = (float)(k / 17 - 8);
    }
    {
        int k4 = (lane < Kwin - 256) ? 256 + lane : 256;
        dxs[4] = (float)(k4 % 17 - 8);
        dys[4] = (float)(k4 / 17 - 8);
    }
    float s4w = (lane < Kwin - 256) ? 1.0f : 0.0f;
    auto LIDX = [&](int s) { return (((size_t)b * Sn + s) * Pn + p) * 2; };
    if (typ == 0) {
        float px = locs[LIDX(0)], py = locs[LIDX(0) + 1];
        if (lane == 0) { nextPts[LIDX(0)] = px; nextPts[LIDX(0) + 1] = py; }
        for (int s = 0; s < 7; s++) {
            lk_track_fly(G + s * FS, G + (s + 1) * FS, px, py, dxs, dys, s4w);
            if (lane == 0) { nextPts[LIDX(s + 1)] = px; nextPts[LIDX(s + 1) + 1] = py; }
        }
        if (lane == 0) { fbackPts[LIDX(7)] = px; fbackPts[LIDX(7) + 1] = py; }
        for (int i = 0; i < 7; i++) {
            lk_track_fly(G + (7 - i) * FS, G + (6 - i) * FS, px, py, dxs, dys, s4w);
            if (lane == 0) { fbackPts[LIDX(6 - i)] = px; fbackPts[LIDX(6 - i) + 1] = py; }
        }
    } else {
        float px = locs[LIDX(7)], py = locs[LIDX(7) + 1];
        if (lane == 0) { backPts[LIDX(7)] = px; backPts[LIDX(7) + 1] = py; }
        for (int i = 0; i < 7; i++) {
            lk_track_fly(G + (7 - i) * FS, G + (6 - i) * FS, px, py, dxs, dys, s4w);
            if (lane == 0) { backPts[LIDX(6 - i)] = px; backPts[LIDX(6 - i) + 1] = py; }
        }
    }
}

// ---------------- launch ----------------
extern "C" void kernel_launch(void* const* d_in, const int* in_sizes, int n_in,
                              void* d_out, int out_size, void* d_ws, size_t ws_size,
                              hipStream_t stream) {
    const float* inputs = (const float*)d_in[0];
    const float* Wdet = (const float*)d_in[1];
    const float* bdet = (const float*)d_in[2];
    float* out = (float*)d_out;

    const size_t N_hm = (size_t)Bn * Sn * Pn * HD * WD;   // 8,912,896
    const size_t N_pts = (size_t)Bn * Sn * Pn * 2;        // 4352
    float* hm = out;
    float* locs = out + N_hm;
    float* scos = locs + N_pts;
    float* nextPts = scos + (size_t)Bn * Sn * Pn;
    float* fbackPts = nextPts + N_pts;
    float* backPts = fbackPts + N_pts;

    const size_t p2_bytes = (size_t)2 * NIMG * P2FR * sizeof(float2);   // ~33.7 MB
    const size_t gray_elems = (size_t)NIMG * HWi;
    if (ws_size >= p2_bytes) {
        float2* P2r = (float2*)d_ws;
        float2* P2rs = P2r + (size_t)NIMG * P2FR;
        mega_kernel<<<NIMG * 64, 256, 0, stream>>>(inputs, Wdet, bdet, hm, P2r, P2rs);
        smax_kernel<<<NIMG * Pn, 256, 0, stream>>>(hm, locs, scos);
        lk_p2_kernel<<<2 * Bn * Pn, 64, 0, stream>>>(P2r, locs, nextPts, fbackPts, backPts);
    } else if (ws_size >= 2 * gray_elems * sizeof(float)) {
        conv_kernel<<<NIMG * 64, 256, 0, stream>>>(inputs, Wdet, bdet, hm);
        smax_kernel<<<NIMG * Pn, 256, 0, stream>>>(hm, locs, scos);
        float* gray = (float*)d_ws;
        float* sh = gray + gray_elems;
        gray2_kernel<<<(NIMG * HWi / 4 + 255) / 256, 256, 0, stream>>>(inputs, gray, sh);
        lk_pair_kernel<<<2 * Bn * Pn, 64, 0, stream>>>(gray, sh, locs, nextPts, fbackPts, backPts);
    } else {
        conv_kernel<<<NIMG * 64, 256, 0, stream>>>(inputs, Wdet, bdet, hm);
        smax_kernel<<<NIMG * Pn, 256, 0, stream>>>(hm, locs, scos);
        lk_fly_kernel<<<2 * Bn * Pn, 64, 0, stream>>>(inputs, locs, nextPts, fbackPts, backPts);
    }
}

// Round 12
// 111.380 us; speedup vs baseline: 1.1286x; 1.0059x over previous
//
#include <hip/hip_runtime.h>
#include <math.h>

// ---------------- problem constants ----------------
namespace {
constexpr int Bn = 4, Sn = 8, Cn = 3, Himg = 256, Wimg = 256;
constexpr int Pn = 68, DS = 4, WIN = 8, STEPS = 10;
constexpr int HWi = Himg * Wimg;            // 65536
constexpr int NIMG = Bn * Sn;               // 32
constexpr int HD = Himg / DS, WD = Wimg / DS; // 64 x 64
constexpr int Kwin = (2 * WIN + 1) * (2 * WIN + 1); // 289
// quad image: Q[k][x] = (g[max(k-1,0)][x], g[min(k,255)][x],
//                        g[max(k-1,0)][min(x+1,255)], g[min(k,255)][min(x+1,255)]), k=0..256
constexpr int QROWS = 257;
constexpr int QFR = QROWS * 256;             // float4 per frame
}

// ---------------- MEGA: conv (3x3 s4) + gray + Q build ----------------
__global__ __launch_bounds__(256) void mega_kernel(const float* __restrict__ x,
                                                   const float* __restrict__ Wdet,
                                                   const float* __restrict__ bdet,
                                                   float* __restrict__ hm,
                                                   float4* __restrict__ Q) {
    __shared__ float wsh[Pn * 27];
    __shared__ float bsh[Pn];
    __shared__ float insh[3][5][Wimg];
    __shared__ float grow[5][257];
    int n = blockIdx.x >> 6;
    int oy = blockIdx.x & 63;
    int tid = threadIdx.x;
    for (int t = tid; t < Pn * 27; t += 256) wsh[t] = Wdet[t];
    if (tid < Pn) bsh[tid] = bdet[tid];
    for (int t = tid; t < 3 * 5 * Wimg; t += 256) {
        int c = t / (5 * Wimg);
        int rem = t % (5 * Wimg);
        int r = rem / Wimg;
        int col = rem % Wimg;
        int gr = min(max(4 * oy - 1 + r, 0), 255);
        insh[c][r][col] = x[(size_t)n * 3 * HWi + (size_t)c * HWi + gr * Wimg + col];
    }
    __syncthreads();
    // ---- conv part (rows 1..3 of the stage) ----
    int ox = tid & 63;
    int wid = tid >> 6;
    float in_reg[27];
    #pragma unroll
    for (int c = 0; c < 3; c++)
        #pragma unroll
        for (int ky = 0; ky < 3; ky++)
            #pragma unroll
            for (int kx = 0; kx < 3; kx++)
                in_reg[c * 9 + ky * 3 + kx] = insh[c][1 + ky][ox * 4 + kx];
    #pragma unroll
    for (int i = 0; i < 17; i++) {
        int p = wid + i * 4;
        const float* w = &wsh[p * 27];
        float acc = bsh[p];
        #pragma unroll
        for (int j = 0; j < 27; j++) acc += w[j] * in_reg[j];
        hm[(size_t)n * Pn * 4096 + (size_t)p * 4096 + oy * 64 + ox] = acc;
    }
    // ---- gray rows 0..4 (input rows clamp(4oy-1 .. 4oy+3)) ----
    #pragma unroll
    for (int r = 0; r < 5; r++)
        grow[r][tid] = 0.299f * insh[0][r][tid] + 0.587f * insh[1][r][tid] + 0.114f * insh[2][r][tid];
    if (tid < 5) grow[tid][256] = grow[tid][255];   // x+1 clamp for col 255
    __syncthreads();
    // ---- Q rows 4oy .. 4oy+3 (+256 at oy=63) ----
    float4* qf = Q + (size_t)n * QFR;
    #pragma unroll
    for (int j = 0; j < 4; j++) {
        int k = 4 * oy + j;
        float4 q;
        q.x = grow[j][tid];
        q.y = grow[j + 1][tid];
        q.z = grow[j][tid + 1];
        q.w = grow[j + 1][tid + 1];
        qf[k * 256 + tid] = q;
    }
    if (oy == 63) {
        float4 q;
        q.x = grow[4][tid];
        q.y = grow[4][tid];
        q.z = grow[4][tid + 1];
        q.w = grow[4][tid + 1];
        qf[256 * 256 + tid] = q;
    }
}

// ---------------- plain conv (fallback tiers) ----------------
__global__ __launch_bounds__(256) void conv_kernel(const float* __restrict__ x,
                                                   const float* __restrict__ Wdet,
                                                   const float* __restrict__ bdet,
                                                   float* __restrict__ hm) {
    __shared__ float wsh[Pn * 27];
    __shared__ float bsh[Pn];
    __shared__ float insh[3][3][Wimg];
    int n = blockIdx.x >> 6;
    int oy = blockIdx.x & 63;
    int tid = threadIdx.x;
    for (int t = tid; t < Pn * 27; t += 256) wsh[t] = Wdet[t];
    if (tid < Pn) bsh[tid] = bdet[tid];
    for (int t = tid; t < 3 * 3 * Wimg; t += 256) {
        int c = t / (3 * Wimg);
        int r = (t / Wimg) % 3;
        int col = t % Wimg;
        insh[c][r][col] = x[(size_t)n * 3 * HWi + (size_t)c * HWi + (oy * 4 + r) * Wimg + col];
    }
    __syncthreads();
    int ox = tid & 63;
    int wid = tid >> 6;
    float in_reg[27];
    #pragma unroll
    for (int c = 0; c < 3; c++)
        #pragma unroll
        for (int ky = 0; ky < 3; ky++)
            #pragma unroll
            for (int kx = 0; kx < 3; kx++)
                in_reg[c * 9 + ky * 3 + kx] = insh[c][ky][ox * 4 + kx];
    #pragma unroll
    for (int i = 0; i < 17; i++) {
        int p = wid + i * 4;
        const float* w = &wsh[p * 27];
        float acc = bsh[p];
        #pragma unroll
        for (int j = 0; j < 27; j++) acc += w[j] * in_reg[j];
        hm[(size_t)n * Pn * 4096 + (size_t)p * 4096 + oy * 64 + ox] = acc;
    }
}

// ---------------- softmax / soft-argmax / scores ----------------
__global__ __launch_bounds__(256) void smax_kernel(const float* __restrict__ hm,
                                                   float* __restrict__ locs,
                                                   float* __restrict__ scos) {
    int row = blockIdx.x;   // n*Pn + p
    const float4* r = (const float4*)(hm + (size_t)row * 4096);
    int tid = threadIdx.x;
    float v[16];
    #pragma unroll
    for (int j = 0; j < 4; j++) {
        float4 q = r[tid + 256 * j];
        v[4 * j + 0] = q.x; v[4 * j + 1] = q.y; v[4 * j + 2] = q.z; v[4 * j + 3] = q.w;
    }
    float m = v[0];
    #pragma unroll
    for (int i = 1; i < 16; i++) m = fmaxf(m, v[i]);
    __shared__ float redm[4];
    #pragma unroll
    for (int o = 32; o; o >>= 1) m = fmaxf(m, __shfl_xor(m, o, 64));
    int wid = tid >> 6, lane = tid & 63;
    if (lane == 0) redm[wid] = m;
    __syncthreads();
    m = fmaxf(fmaxf(redm[0], redm[1]), fmaxf(redm[2], redm[3]));
    float s = 0.f, sx = 0.f, sy = 0.f;
    #pragma unroll
    for (int j = 0; j < 4; j++) {
        #pragma unroll
        for (int q = 0; q < 4; q++) {
            int e = (tid + 256 * j) * 4 + q;
            float ev = expf(v[4 * j + q] - m);
            s += ev;
            sx += ev * (float)(e & 63);
            sy += ev * (float)(e >> 6);
        }
    }
    #pragma unroll
    for (int o = 32; o; o >>= 1) {
        s  += __shfl_xor(s, o, 64);
        sx += __shfl_xor(sx, o, 64);
        sy += __shfl_xor(sy, o, 64);
    }
    __shared__ float reds[3][4];
    if (lane == 0) { reds[0][wid] = s; reds[1][wid] = sx; reds[2][wid] = sy; }
    __syncthreads();
    if (tid == 0) {
        float S_ = reds[0][0] + reds[0][1] + reds[0][2] + reds[0][3];
        float SX = reds[1][0] + reds[1][1] + reds[1][2] + reds[1][3];
        float SY = reds[2][0] + reds[2][1] + reds[2][2] + reds[2][3];
        locs[(size_t)row * 2 + 0] = SX / S_ * 4.0f;
        locs[(size_t)row * 2 + 1] = SY / S_ * 4.0f;
        scos[row] = m;
    }
}

// ---------------- DPP wave64 sum reduction (VALU-only) ----------------
template <int CTRL>
__device__ inline float dpp_add(float v) {
    int t = __builtin_amdgcn_update_dpp(0, __builtin_bit_cast(int, v), CTRL, 0xF, 0xF, true);
    return v + __builtin_bit_cast(float, t);
}

__device__ inline float wredw(float v) {
    v = dpp_add<0x111>(v);   // row_shr:1
    v = dpp_add<0x112>(v);   // row_shr:2
    v = dpp_add<0x114>(v);   // row_shr:4
    v = dpp_add<0x118>(v);   // row_shr:8
    v = dpp_add<0x142>(v);   // row_bcast:15
    v = dpp_add<0x143>(v);   // row_bcast:31
    int s = __builtin_amdgcn_readlane(__builtin_bit_cast(int, v), 63);
    return __builtin_bit_cast(float, s);
}

// ---------------- LK track step on quad image (1 wave/chain) ----------------
// All gathers are 16B-aligned float4; no parity select. Iter-0 prefetch kept.
__device__ void lk_track_q(const float4* __restrict__ Qo, const float4* __restrict__ Qn,
                           float& px, float& py, const float* dxs, const float* dys,
                           float s4w) {
    const float XM = (float)(Wimg - 1.001);
    const float YM = (float)(Himg - 1.001);
    float I0[5], Ix[5], Iy[5], qx[5], qy[5];
    float wx[5], wy[5];
    float4 Q0[5];
    // ---- template phase + iter-0 prefetch ----
    {
        int idA[5], idS[5], xm[5], xp[5];
        #pragma unroll
        for (int j = 0; j < 5; j++) {
            qx[j] = px + dxs[j];
            qy[j] = py + dys[j];
            float x = fminf(fmaxf(qx[j], 0.0f), XM);
            float y = fminf(fmaxf(qy[j], 0.0f), YM);
            float xf = floorf(x), yf = floorf(y);
            wx[j] = x - xf; wy[j] = y - yf;
            int xi = (int)xf, yi = (int)yf;
            idA[j] = yi * 256 + xi;
            idS[j] = (yi + 1) * 256;
            xm[j] = max(xi - 1, 0);
            xp[j] = min(xi + 2, Wimg - 1);
        }
        float4 A[5], B[5];
        float2 S1[5], S2[5];
        #pragma unroll
        for (int j = 0; j < 5; j++) {
            A[j] = Qo[idA[j]];                                            // (m0,c00,m1,c01)
            B[j] = Qo[idA[j] + 512];                                      // (c10,p0,c11,p1)
            S1[j] = *reinterpret_cast<const float2*>(Qo + idS[j] + xm[j]); // (c0m,c1m)
            S2[j] = *reinterpret_cast<const float2*>(Qo + idS[j] + xp[j]); // (c0p,c1p)
            Q0[j] = Qn[idA[j] + 256];                                     // iter-0 (v00,v10,v01,v11)
        }
        #pragma unroll
        for (int j = 0; j < 5; j++) {
            float m0 = A[j].x, c00 = A[j].y, m1 = A[j].z, c01 = A[j].w;
            float c10 = B[j].x, p0 = B[j].y, c11 = B[j].z, p1 = B[j].w;
            float c0m = S1[j].x, c1m = S1[j].y, c0p = S2[j].x, c1p = S2[j].y;
            float u = 1.0f - wx[j], t = 1.0f - wy[j];
            I0[j] = t * (u * c00 + wx[j] * c01) + wy[j] * (u * c10 + wx[j] * c11);
            float gx00 = 0.5f * (c01 - c0m);
            float gx01 = 0.5f * (c0p - c00);
            float gx10 = 0.5f * (c11 - c1m);
            float gx11 = 0.5f * (c1p - c10);
            Ix[j] = t * (u * gx00 + wx[j] * gx01) + wy[j] * (u * gx10 + wx[j] * gx11);
            float gy00 = 0.5f * (c10 - m0);
            float gy01 = 0.5f * (c11 - m1);
            float gy10 = 0.5f * (p0 - c00);
            float gy11 = 0.5f * (p1 - c01);
            Iy[j] = t * (u * gy00 + wx[j] * gy01) + wy[j] * (u * gy10 + wx[j] * gy11);
        }
        Ix[4] *= s4w;
        Iy[4] *= s4w;
    }
    float gxx = 0.f, gxy = 0.f, gyy = 0.f;
    #pragma unroll
    for (int j = 0; j < 5; j++) { gxx += Ix[j] * Ix[j]; gxy += Ix[j] * Iy[j]; gyy += Iy[j] * Iy[j]; }
    gxx = wredw(gxx); gxy = wredw(gxy); gyy = wredw(gyy);
    float det = gxx * gyy - gxy * gxy + 1e-6f;
    float A = gyy / det, Bv = -gxy / det, D = gxx / det;  // Ginv
    float vx = 0.f, vy = 0.f;
    // ---- iter 0 from prefetched Q0 (fx==wx, fy==wy bitwise) ----
    {
        float bx = 0.f, by = 0.f;
        #pragma unroll
        for (int j = 0; j < 5; j++) {
            float u = 1.0f - wx[j], t = 1.0f - wy[j];
            float I1 = t * (u * Q0[j].x + wx[j] * Q0[j].z) + wy[j] * (u * Q0[j].y + wx[j] * Q0[j].w);
            float err = I0[j] - I1;
            bx += err * Ix[j];
            by += err * Iy[j];
        }
        bx = wredw(bx); by = wredw(by);
        vx += A * bx + Bv * by;
        vy += Bv * bx + D * by;
    }
    // ---- iters 1..9: 5 aligned dwordx4 gathers per iter ----
    for (int it = 1; it < STEPS; ++it) {
        float fx[5], fy[5];
        int id[5];
        #pragma unroll
        for (int j = 0; j < 5; j++) {
            float x = fminf(fmaxf(qx[j] + vx, 0.0f), XM);
            float y = fminf(fmaxf(qy[j] + vy, 0.0f), YM);
            float xf = floorf(x), yf = floorf(y);
            fx[j] = x - xf; fy[j] = y - yf;
            int xi = (int)xf, yi = (int)yf;
            id[j] = (yi + 1) * 256 + xi;
        }
        float4 Qv[5];
        #pragma unroll
        for (int j = 0; j < 5; j++) Qv[j] = Qn[id[j]];
        float bx = 0.f, by = 0.f;
        #pragma unroll
        for (int j = 0; j < 5; j++) {
            // Qv = (v00, v10, v01, v11)
            float u = 1.0f - fx[j], t = 1.0f - fy[j];
            float I1 = t * (u * Qv[j].x + fx[j] * Qv[j].z) + fy[j] * (u * Qv[j].y + fx[j] * Qv[j].w);
            float err = I0[j] - I1;
            bx += err * Ix[j];
            by += err * Iy[j];
        }
        bx = wredw(bx); by = wredw(by);
        vx += A * bx + Bv * by;
        vy += Bv * bx + D * by;
    }
    px += vx; py += vy;
}

__global__ __launch_bounds__(64) void lk_q_kernel(const float4* __restrict__ Q,
                                                  const float* __restrict__ locs,
                                                  float* __restrict__ nextPts,
                                                  float* __restrict__ fbackPts,
                                                  float* __restrict__ backPts) {
    int g = blockIdx.x;
    int typ = g / (Bn * Pn);
    int r = g % (Bn * Pn);
    int b = r / Pn;
    int p = r % Pn;
    int lane = threadIdx.x;
    const float4* F = Q + (size_t)b * Sn * QFR;
    float dxs[5], dys[5];
    #pragma unroll
    for (int j = 0; j < 4; j++) {
        int k = lane + 64 * j;
        dxs[j] = (float)(k % 17 - 8);
        dys[j] = (float)(k / 17 - 8);
    }
    {
        int k4 = (lane < Kwin - 256) ? 256 + lane : 256;
        dxs[4] = (float)(k4 % 17 - 8);
        dys[4] = (float)(k4 / 17 - 8);
    }
    float s4w = (lane < Kwin - 256) ? 1.0f : 0.0f;
    auto LIDX = [&](int s) { return (((size_t)b * Sn + s) * Pn + p) * 2; };
    if (typ == 0) {
        float px = locs[LIDX(0)], py = locs[LIDX(0) + 1];
        if (lane == 0) { nextPts[LIDX(0)] = px; nextPts[LIDX(0) + 1] = py; }
        for (int s = 0; s < 7; s++) {
            lk_track_q(F + s * QFR, F + (s + 1) * QFR, px, py, dxs, dys, s4w);
            if (lane == 0) { nextPts[LIDX(s + 1)] = px; nextPts[LIDX(s + 1) + 1] = py; }
        }
        if (lane == 0) { fbackPts[LIDX(7)] = px; fbackPts[LIDX(7) + 1] = py; }
        for (int i = 0; i < 7; i++) {
            lk_track_q(F + (7 - i) * QFR, F + (6 - i) * QFR, px, py, dxs, dys, s4w);
            if (lane == 0) { fbackPts[LIDX(6 - i)] = px; fbackPts[LIDX(6 - i) + 1] = py; }
        }
    } else {
        float px = locs[LIDX(7)], py = locs[LIDX(7) + 1];
        if (lane == 0) { backPts[LIDX(7)] = px; backPts[LIDX(7) + 1] = py; }
        for (int i = 0; i < 7; i++) {
            lk_track_q(F + (7 - i) * QFR, F + (6 - i) * QFR, px, py, dxs, dys, s4w);
            if (lane == 0) { backPts[LIDX(6 - i)] = px; backPts[LIDX(6 - i) + 1] = py; }
        }
    }
}

// ================= fallback tier 3: on-the-fly gray =================
__device__ inline float px_fly(const float* __restrict__ im, int idx) {
    return 0.299f * im[idx] + 0.587f * im[idx + HWi] + 0.114f * im[idx + 2 * HWi];
}

__device__ void lk_track_fly(const float* __restrict__ oldI, const float* __restrict__ newI,
                             float& px, float& py, const float* dxs, const float* dys,
                             float s4w) {
    const float XM = (float)(Wimg - 1.001);
    const float YM = (float)(Himg - 1.001);
    float I0[5], Ix[5], Iy[5], qx[5], qy[5];
    {
        float wx[5], wy[5];
        int am[5], a0[5], a1[5], ap[5], xm[5], x0[5], x1[5], xp[5];
        #pragma unroll
        for (int j = 0; j < 5; j++) {
            qx[j] = px + dxs[j]; qy[j] = py + dys[j];
            float x = fminf(fmaxf(qx[j], 0.0f), XM);
            float y = fminf(fmaxf(qy[j], 0.0f), YM);
            float x0f = floorf(x), y0f = floorf(y);
            wx[j] = x - x0f; wy[j] = y - y0f;
            int xi = (int)x0f, yi = (int)y0f;
            x0[j] = xi; x1[j] = min(xi + 1, Wimg - 1);
            xm[j] = max(xi - 1, 0); xp[j] = min(xi + 2, Wimg - 1);
            a0[j] = yi * Wimg;
            a1[j] = min(yi + 1, Himg - 1) * Wimg;
            am[j] = max(yi - 1, 0) * Wimg;
            ap[j] = min(yi + 2, Himg - 1) * Wimg;
        }
        #pragma unroll
        for (int j = 0; j < 5; j++) {
            float m0 = px_fly(oldI, am[j] + x0[j]), m1 = px_fly(oldI, am[j] + x1[j]);
            float c0m = px_fly(oldI, a0[j] + xm[j]), c00 = px_fly(oldI, a0[j] + x0[j]);
            float c01 = px_fly(oldI, a0[j] + x1[j]), c0p = px_fly(oldI, a0[j] + xp[j]);
            float c1m = px_fly(oldI, a1[j] + xm[j]), c10 = px_fly(oldI, a1[j] + x0[j]);
            float c11 = px_fly(oldI, a1[j] + x1[j]), c1p = px_fly(oldI, a1[j] + xp[j]);
            float p0 = px_fly(oldI, ap[j] + x0[j]), p1 = px_fly(oldI, ap[j] + x1[j]);
            float u = 1.0f - wx[j], t = 1.0f - wy[j];
            I0[j] = t * (u * c00 + wx[j] * c01) + wy[j] * (u * c10 + wx[j] * c11);
            Ix[j] = t * (u * 0.5f * (c01 - c0m) + wx[j] * 0.5f * (c0p - c00))
                  + wy[j] * (u * 0.5f * (c11 - c1m) + wx[j] * 0.5f * (c1p - c10));
            Iy[j] = t * (u * 0.5f * (c10 - m0) + wx[j] * 0.5f * (c11 - m1))
                  + wy[j] * (u * 0.5f * (p0 - c00) + wx[j] * 0.5f * (p1 - c01));
        }
        Ix[4] *= s4w; Iy[4] *= s4w;
    }
    float gxx = 0.f, gxy = 0.f, gyy = 0.f;
    #pragma unroll
    for (int j = 0; j < 5; j++) { gxx += Ix[j] * Ix[j]; gxy += Ix[j] * Iy[j]; gyy += Iy[j] * Iy[j]; }
    gxx = wredw(gxx); gxy = wredw(gxy); gyy = wredw(gyy);
    float det = gxx * gyy - gxy * gxy + 1e-6f;
    float A = gyy / det, Bv = -gxy / det, D = gxx / det;
    float vx = 0.f, vy = 0.f;
    for (int it = 0; it < STEPS; ++it) {
        float bx = 0.f, by = 0.f;
        #pragma unroll
        for (int j = 0; j < 5; j++) {
            float x = fminf(fmaxf(qx[j] + vx, 0.0f), XM);
            float y = fminf(fmaxf(qy[j] + vy, 0.0f), YM);
            float x0f = floorf(x), y0f = floorf(y);
            float fxx = x - x0f, fyy = y - y0f;
            int xi = (int)x0f, yi = (int)y0f;
            int ad = yi * Wimg + xi;
            int d1 = (xi < Wimg - 1) ? 1 : 0;
            int d2 = (yi < Himg - 1) ? Wimg : 0;
            float v00 = px_fly(newI, ad), v01 = px_fly(newI, ad + d1);
            float v10 = px_fly(newI, ad + d2), v11 = px_fly(newI, ad + d2 + d1);
            float u = 1.0f - fxx, t = 1.0f - fyy;
            float I1 = t * (u * v00 + fxx * v01) + fyy * (u * v10 + fxx * v11);
            float err = I0[j] - I1;
            bx += err * Ix[j];
            by += err * Iy[j];
        }
        bx = wredw(bx); by = wredw(by);
        vx += A * bx + Bv * by;
        vy += Bv * bx + D * by;
    }
    px += vx; py += vy;
}

__global__ __launch_bounds__(64) void lk_fly_kernel(const float* __restrict__ in,
                                                    const float* __restrict__ locs,
                                                    float* __restrict__ nextPts,
                                                    float* __restrict__ fbackPts,
                                                    float* __restrict__ backPts) {
    constexpr size_t FS = (size_t)3 * HWi;
    int g = blockIdx.x;
    int typ = g / (Bn * Pn);
    int r = g % (Bn * Pn);
    int b = r / Pn;
    int p = r % Pn;
    int lane = threadIdx.x;
    const float* G = in + (size_t)b * Sn * FS;
    float dxs[5], dys[5];
    #pragma unroll
    for (int j = 0; j < 4; j++) {
        int k = lane + 64 * j;
        dxs[j] = (float)(k % 17 - 8);
        dys[j] = (float)(k / 17 - 8);
    }
    {
        int k4 = (lane < Kwin - 256) ? 256 + lane : 256;
        dxs[4] = (float)(k4 % 17 - 8);
        dys[4] = (float)(k4 / 17 - 8);
    }
    float s4w = (lane < Kwin - 256) ? 1.0f : 0.0f;
    auto LIDX = [&](int s) { return (((size_t)b * Sn + s) * Pn + p) * 2; };
    if (typ == 0) {
        float px = locs[LIDX(0)], py = locs[LIDX(0) + 1];
        if (lane == 0) { nextPts[LIDX(0)] = px; nextPts[LIDX(0) + 1] = py; }
        for (int s = 0; s < 7; s++) {
            lk_track_fly(G + s * FS, G + (s + 1) * FS, px, py, dxs, dys, s4w);
            if (lane == 0) { nextPts[LIDX(s + 1)] = px; nextPts[LIDX(s + 1) + 1] = py; }
        }
        if (lane == 0) { fbackPts[LIDX(7)] = px; fbackPts[LIDX(7) + 1] = py; }
        for (int i = 0; i < 7; i++) {
            lk_track_fly(G + (7 - i) * FS, G + (6 - i) * FS, px, py, dxs, dys, s4w);
            if (lane == 0) { fbackPts[LIDX(6 - i)] = px; fbackPts[LIDX(6 - i) + 1] = py; }
        }
    } else {
        float px = locs[LIDX(7)], py = locs[LIDX(7) + 1];
        if (lane == 0) { backPts[LIDX(7)] = px; backPts[LIDX(7) + 1] = py; }
        for (int i = 0; i < 7; i++) {
            lk_track_fly(G + (7 - i) * FS, G + (6 - i) * FS, px, py, dxs, dys, s4w);
            if (lane == 0) { backPts[LIDX(6 - i)] = px; backPts[LIDX(6 - i) + 1] = py; }
        }
    }
}

// ---------------- launch ----------------
extern "C" void kernel_launch(void* const* d_in, const int* in_sizes, int n_in,
                              void* d_out, int out_size, void* d_ws, size_t ws_size,
                              hipStream_t stream) {
    const float* inputs = (const float*)d_in[0];
    const float* Wdet = (const float*)d_in[1];
    const float* bdet = (const float*)d_in[2];
    float* out = (float*)d_out;

    const size_t N_hm = (size_t)Bn * Sn * Pn * HD * WD;   // 8,912,896
    const size_t N_pts = (size_t)Bn * Sn * Pn * 2;        // 4352
    float* hm = out;
    float* locs = out + N_hm;
    float* scos = locs + N_pts;
    float* nextPts = scos + (size_t)Bn * Sn * Pn;
    float* fbackPts = nextPts + N_pts;
    float* backPts = fbackPts + N_pts;

    const size_t q_bytes = (size_t)NIMG * QFR * sizeof(float4);   // ~33.7 MB
    if (ws_size >= q_bytes) {
        float4* Q = (float4*)d_ws;
        mega_kernel<<<NIMG * 64, 256, 0, stream>>>(inputs, Wdet, bdet, hm, Q);
        smax_kernel<<<NIMG * Pn, 256, 0, stream>>>(hm, locs, scos);
        lk_q_kernel<<<2 * Bn * Pn, 64, 0, stream>>>(Q, locs, nextPts, fbackPts, backPts);
    } else {
        conv_kernel<<<NIMG * 64, 256, 0, stream>>>(inputs, Wdet, bdet, hm);
        smax_kernel<<<NIMG * Pn, 256, 0, stream>>>(hm, locs, scos);
        lk_fly_kernel<<<2 * Bn * Pn, 64, 0, stream>>>(inputs, locs, nextPts, fbackPts, backPts);
    }
}